// Round 1
// baseline (7157.381 us; speedup 1.0000x reference)
//
#include <hip/hip_runtime.h>
#include <math.h>

// Problem constants
constexpr int cB = 4, cS = 2048, cD = 1024, cH = 8, cE = 8, cK = 2, cDH = 128;
constexpr int cBS = cB * cS;          // 8192
constexpr int cHE = cH * cE;          // 64
constexpr int cNSEL = cBS * cH * cK;  // 131072 selections (per routing side)

// ---------------------------------------------------------------------------
// K1: gates — per block: 8 rows of x; compute sigmoid(x @ sel^T) for v and o,
// top-2 per (row,h), write weights/indices, histogram bucket counts.
// ---------------------------------------------------------------------------
__global__ __launch_bounds__(256) void k_gates(
    const float* __restrict__ x, const float* __restrict__ sel_v,
    const float* __restrict__ sel_o,
    float* __restrict__ vw, int* __restrict__ vi,
    float* __restrict__ ow, int* __restrict__ oi,
    int* __restrict__ v_cnt, int* __restrict__ o_cnt)
{
    __shared__ float xs[8][cD];       // 32 KB
    __shared__ float gs[8][2 * cHE];  // 4 KB: raw logits, [row][p] p<64: v, else o
    const int row0 = blockIdx.x * 8;
    const int t = threadIdx.x;

    // load 8 rows of x (float4, coalesced)
    const float4* xv = (const float4*)(x + (size_t)row0 * cD);
    float4* xsv = (float4*)&xs[0][0];
    for (int i = t; i < 8 * cD / 4; i += 256) xsv[i] = xv[i];
    __syncthreads();

    const int wave = t >> 6, lane = t & 63;
    for (int p = wave; p < 2 * cHE; p += 4) {
        const float* srow = (p < cHE) ? (sel_v + (size_t)p * cD)
                                      : (sel_o + (size_t)(p - cHE) * cD);
        float acc[8] = {0, 0, 0, 0, 0, 0, 0, 0};
        for (int d = lane; d < cD; d += 64) {
            float w = srow[d];
#pragma unroll
            for (int r = 0; r < 8; r++) acc[r] += w * xs[r][d];
        }
#pragma unroll
        for (int off = 32; off > 0; off >>= 1) {
#pragma unroll
            for (int r = 0; r < 8; r++) acc[r] += __shfl_down(acc[r], off);
        }
        if (lane == 0) {
            for (int r = 0; r < 8; r++) gs[r][p] = acc[r];
        }
    }
    __syncthreads();

    // top-2 per (row, h, which): 8*8*2 = 128 tasks
    if (t < 128) {
        const int r = t >> 4, h = (t >> 1) & 7, which = t & 1;
        const float* g = &gs[r][which * cHE + h * cE];
        int i0 = 0; float b0 = g[0];
        for (int e = 1; e < cE; e++) { if (g[e] > b0) { b0 = g[e]; i0 = e; } }
        int i1 = -1; float b1 = -3.0e38f;
        for (int e = 0; e < cE; e++) { if (e != i0 && g[e] > b1) { b1 = g[e]; i1 = e; } }
        const float w0 = 1.0f / (1.0f + expf(-b0));
        const float w1 = 1.0f / (1.0f + expf(-b1));
        const int base = ((row0 + r) * cH + h) * cK;
        if (which == 0) {
            vw[base] = w0; vi[base] = i0; vw[base + 1] = w1; vi[base + 1] = i1;
            atomicAdd(&v_cnt[h * cE + i0], 1); atomicAdd(&v_cnt[h * cE + i1], 1);
        } else {
            ow[base] = w0; oi[base] = i0; ow[base + 1] = w1; oi[base + 1] = i1;
            atomicAdd(&o_cnt[h * cE + i0], 1); atomicAdd(&o_cnt[h * cE + i1], 1);
        }
    }
}

// ---------------------------------------------------------------------------
// K2a: exclusive prefix of bucket counts; zero cursors. 1 block.
// ---------------------------------------------------------------------------
__global__ void k_prefix(const int* __restrict__ v_cnt, const int* __restrict__ o_cnt,
                         int* __restrict__ v_off, int* __restrict__ o_off,
                         int* __restrict__ v_cur, int* __restrict__ o_cur)
{
    if (threadIdx.x == 0) {
        int a = 0;
        for (int i = 0; i < cHE; i++) { v_off[i] = a; a += v_cnt[i]; }
        v_off[cHE] = a;
        a = 0;
        for (int i = 0; i < cHE; i++) { o_off[i] = a; a += o_cnt[i]; }
        o_off[cHE] = a;
    }
    if (threadIdx.x < cHE) { v_cur[threadIdx.x] = 0; o_cur[threadIdx.x] = 0; }
}

// ---------------------------------------------------------------------------
// K2b: scatter selections into per-(h,e) buckets (row id = bs*H+h, weight).
// ---------------------------------------------------------------------------
__global__ __launch_bounds__(256) void k_scatter(
    const float* __restrict__ vw, const int* __restrict__ vi,
    const float* __restrict__ ow, const int* __restrict__ oi,
    const int* __restrict__ v_off, const int* __restrict__ o_off,
    int* __restrict__ v_cur, int* __restrict__ o_cur,
    int* __restrict__ v_row, float* __restrict__ v_wl,
    int* __restrict__ o_row, float* __restrict__ o_wl)
{
    const int idx = blockIdx.x * 256 + threadIdx.x;  // [0, 2*cNSEL)
    const int which = (idx >= cNSEL) ? 1 : 0;
    const int sel = which ? idx - cNSEL : idx;       // ((bs*H + h)*K + j)
    const int rh = sel >> 1;                          // bs*H + h
    const int h = rh & (cH - 1);
    if (!which) {
        const int e = vi[sel], bkt = h * cE + e;
        const int pos = atomicAdd(&v_cur[bkt], 1) + v_off[bkt];
        v_row[pos] = rh; v_wl[pos] = vw[sel];
    } else {
        const int e = oi[sel], bkt = h * cE + e;
        const int pos = atomicAdd(&o_cur[bkt], 1) + o_off[bkt];
        o_row[pos] = rh; o_wl[pos] = ow[sel];
    }
}

// ---------------------------------------------------------------------------
// K4: Q/K projection. 128x128 output tiles, KC=16, micro 8x8 per thread.
// Writes into [B,H,S,DH] layout. y<8: Q head y; y>=8: K head y-8.
// ---------------------------------------------------------------------------
__global__ __launch_bounds__(256) void k_qkproj(
    const float* __restrict__ x, const float* __restrict__ Wq,
    const float* __restrict__ Wk, float* __restrict__ q_t, float* __restrict__ k_t)
{
    const int rt = blockIdx.x;    // 64 row tiles of 128 (over b*S+s)
    const int nt = blockIdx.y;    // 16: 0..7 Q heads, 8..15 K heads
    const bool isK = nt >= cH;
    const int h = isK ? nt - cH : nt;
    const float* W = (isK ? Wk : Wq) + (size_t)h * cDH * cD;
    float* outp = isK ? k_t : q_t;

    __shared__ float at[128][17];
    __shared__ float bt[128][17];
    const int t = threadIdx.x, ty = t >> 4, tx = t & 15;

    float acc[8][8];
#pragma unroll
    for (int i = 0; i < 8; i++)
#pragma unroll
        for (int j = 0; j < 8; j++) acc[i][j] = 0.0f;

    const int r0 = rt * 128;
    const int lr = t >> 1, lc = (t & 1) * 8;
    for (int kc = 0; kc < cD; kc += 16) {
        const float* ap = x + (size_t)(r0 + lr) * cD + kc + lc;
        float4 a0 = *(const float4*)ap;
        float4 a1 = *(const float4*)(ap + 4);
        at[lr][lc + 0] = a0.x; at[lr][lc + 1] = a0.y; at[lr][lc + 2] = a0.z; at[lr][lc + 3] = a0.w;
        at[lr][lc + 4] = a1.x; at[lr][lc + 5] = a1.y; at[lr][lc + 6] = a1.z; at[lr][lc + 7] = a1.w;
        const float* bp = W + (size_t)lr * cD + kc + lc;
        float4 b0 = *(const float4*)bp;
        float4 b1 = *(const float4*)(bp + 4);
        bt[lr][lc + 0] = b0.x; bt[lr][lc + 1] = b0.y; bt[lr][lc + 2] = b0.z; bt[lr][lc + 3] = b0.w;
        bt[lr][lc + 4] = b1.x; bt[lr][lc + 5] = b1.y; bt[lr][lc + 6] = b1.z; bt[lr][lc + 7] = b1.w;
        __syncthreads();
#pragma unroll 4
        for (int d = 0; d < 16; d++) {
            float av[8], bv[8];
#pragma unroll
            for (int i = 0; i < 8; i++) av[i] = at[ty * 8 + i][d];
#pragma unroll
            for (int j = 0; j < 8; j++) bv[j] = bt[tx * 8 + j][d];
#pragma unroll
            for (int i = 0; i < 8; i++)
#pragma unroll
                for (int j = 0; j < 8; j++) acc[i][j] += av[i] * bv[j];
        }
        __syncthreads();
    }
#pragma unroll
    for (int i = 0; i < 8; i++) {
        const int r = r0 + ty * 8 + i;
        const int b = r >> 11, s = r & (cS - 1);
        float* dst = outp + ((size_t)(b * cH + h) * cS + s) * cDH + tx * 8;
        *(float4*)dst = make_float4(acc[i][0], acc[i][1], acc[i][2], acc[i][3]);
        *(float4*)(dst + 4) = make_float4(acc[i][4], acc[i][5], acc[i][6], acc[i][7]);
    }
}

// ---------------------------------------------------------------------------
// K4b: in-place RoPE on q_t and k_t ([B,H,S,DH], full rotation, base 10000).
// ---------------------------------------------------------------------------
__global__ __launch_bounds__(256) void k_rope(
    float* __restrict__ q_t, float* __restrict__ k_t,
    const int* __restrict__ positions)
{
    const int total = cB * cH * cS * (cDH / 2);
    const int idx = blockIdx.x * 256 + threadIdx.x;  // [0, 2*total)
    const int which = (idx >= total) ? 1 : 0;
    const int id = which ? idx - total : idx;
    const int i = id & 63;
    const int bhs = id >> 6;                  // (b*H+h)*S + s
    const int s = bhs & (cS - 1);
    const int b = (bhs >> 11) >> 3;
    float* base = (which ? k_t : q_t) + (size_t)bhs * cDH;
    const int pos = positions[b * cS + s];
    const float freq = powf(10000.0f, -(float)i / 64.0f);
    const float ang = (float)pos * freq;
    const float c = cosf(ang), sn = sinf(ang);
    const float t1 = base[i], t2 = base[i + 64];
    base[i] = t1 * c - t2 * sn;
    base[i + 64] = t2 * c + t1 * sn;
}

// ---------------------------------------------------------------------------
// K3: V expert GEMM, bucketed. Block = (tile of <=64 rows, bucket (h,e)).
// v_t[b,h,s,:] += w * (x[bs,:] @ Wv[h,e])  via atomicAdd (2 experts/row).
// ---------------------------------------------------------------------------
__global__ __launch_bounds__(256) void k_vexp(
    const float* __restrict__ x, const float* __restrict__ Wv,
    const int* __restrict__ v_off, const int* __restrict__ v_cnt,
    const int* __restrict__ v_row, const float* __restrict__ v_wl,
    float* __restrict__ v_t)
{
    const int bkt = blockIdx.y;
    const int cnt = v_cnt[bkt];
    const int r0 = blockIdx.x * 64;
    if (r0 >= cnt) return;
    const int n = min(64, cnt - r0);
    const int base = v_off[bkt] + r0;

    __shared__ int rows[64];
    __shared__ float rws[64];
    __shared__ float xt[64][33];
    __shared__ float wt[32][128];
    const int t = threadIdx.x, ty = t >> 4, tx = t & 15;
    if (t < 64) {
        rows[t] = v_row[base + min(t, n - 1)];
        rws[t] = (t < n) ? v_wl[base + t] : 0.0f;
    }
    __syncthreads();

    const float* wv = Wv + (size_t)bkt * cD * cDH;
    float acc[4][8];
#pragma unroll
    for (int i = 0; i < 4; i++)
#pragma unroll
        for (int j = 0; j < 8; j++) acc[i][j] = 0.0f;

    const int lr = t >> 2, lc = (t & 3) * 8;
    for (int kc = 0; kc < cD; kc += 32) {
        {
            const int bs = rows[lr] >> 3;
            const float* xp = x + (size_t)bs * cD + kc + lc;
            float4 a = *(const float4*)xp;
            float4 b2 = *(const float4*)(xp + 4);
            float* dst = &xt[lr][lc];
            dst[0] = a.x; dst[1] = a.y; dst[2] = a.z; dst[3] = a.w;
            dst[4] = b2.x; dst[5] = b2.y; dst[6] = b2.z; dst[7] = b2.w;
        }
        {
            const float4* src = (const float4*)(wv + (size_t)kc * cDH);
            float4* dst = (float4*)&wt[0][0];
            for (int i = t; i < 32 * cDH / 4; i += 256) dst[i] = src[i];
        }
        __syncthreads();
#pragma unroll 8
        for (int d = 0; d < 32; d++) {
            const float a0 = xt[ty * 4 + 0][d], a1 = xt[ty * 4 + 1][d];
            const float a2 = xt[ty * 4 + 2][d], a3 = xt[ty * 4 + 3][d];
#pragma unroll
            for (int j = 0; j < 8; j++) {
                const float bv = wt[d][tx * 8 + j];
                acc[0][j] += a0 * bv; acc[1][j] += a1 * bv;
                acc[2][j] += a2 * bv; acc[3][j] += a3 * bv;
            }
        }
        __syncthreads();
    }
#pragma unroll
    for (int i = 0; i < 4; i++) {
        const int r = ty * 4 + i;
        if (r < n) {
            const int rbsh = rows[r];
            const float w = rws[r];
            const int h = rbsh & 7, bs = rbsh >> 3;
            const int b = bs >> 11, s = bs & (cS - 1);
            float* dst = v_t + ((size_t)(b * cH + h) * cS + s) * cDH + tx * 8;
#pragma unroll
            for (int j = 0; j < 8; j++) atomicAdd(&dst[j], w * acc[i][j]);
        }
    }
}

// ---------------------------------------------------------------------------
// K5: causal flash attention. Block = (q-tile 64, h, b); k-tiles of 32.
// ---------------------------------------------------------------------------
__global__ __launch_bounds__(256) void k_attn(
    const float* __restrict__ q_t, const float* __restrict__ k_t,
    const float* __restrict__ v_t, float* __restrict__ ctx)
{
    const int qt = blockIdx.x, h = blockIdx.y, b = blockIdx.z;
    __shared__ float qs[64][132];
    __shared__ float ks[32][132];
    __shared__ float vs[32][132];
    __shared__ float ps[64][33];
    const int t = threadIdx.x, ty = t >> 4, tx = t & 15;
    const size_t hb = (size_t)(b * cH + h) * cS;
    const float* qbase = q_t + hb * cDH;
    const float* kbase = k_t + hb * cDH;
    const float* vbase = v_t + hb * cDH;
    const int q0 = qt * 64;

    for (int i = t; i < 64 * 32; i += 256) {
        const int r = i >> 5, c = (i & 31) * 4;
        *(float4*)&qs[r][c] = *(const float4*)(qbase + (size_t)(q0 + r) * cDH + c);
    }

    float m[4], l[4], o[4][8];
#pragma unroll
    for (int i = 0; i < 4; i++) {
        m[i] = -1.0e30f; l[i] = 0.0f;
#pragma unroll
        for (int j = 0; j < 8; j++) o[i][j] = 0.0f;
    }
    const float scale = 0.08838834764831845f;  // 1/sqrt(128)
    const int nkt = qt * 2 + 2;

    for (int kt = 0; kt < nkt; kt++) {
        const int k0 = kt * 32;
        __syncthreads();
        for (int i = t; i < 32 * 32; i += 256) {
            const int r = i >> 5, c = (i & 31) * 4;
            *(float4*)&ks[r][c] = *(const float4*)(kbase + (size_t)(k0 + r) * cDH + c);
            *(float4*)&vs[r][c] = *(const float4*)(vbase + (size_t)(k0 + r) * cDH + c);
        }
        __syncthreads();

        float sc[4][2];
#pragma unroll
        for (int i = 0; i < 4; i++) { sc[i][0] = 0.0f; sc[i][1] = 0.0f; }
#pragma unroll 4
        for (int d = 0; d < cDH; d++) {
            const float k0v = ks[tx * 2 + 0][d];
            const float k1v = ks[tx * 2 + 1][d];
#pragma unroll
            for (int i = 0; i < 4; i++) {
                const float qv = qs[ty * 4 + i][d];
                sc[i][0] += qv * k0v;
                sc[i][1] += qv * k1v;
            }
        }
#pragma unroll
        for (int i = 0; i < 4; i++) {
            const int qg = q0 + ty * 4 + i;
#pragma unroll
            for (int j = 0; j < 2; j++) {
                const int kg = k0 + tx * 2 + j;
                sc[i][j] = (kg <= qg) ? sc[i][j] * scale : -1.0e30f;
            }
        }
        // online softmax (rows live in one 16-lane tx-group)
        float mt[4], alpha[4], rs[4];
#pragma unroll
        for (int i = 0; i < 4; i++) mt[i] = fmaxf(sc[i][0], sc[i][1]);
#pragma unroll
        for (int off = 1; off < 16; off <<= 1) {
#pragma unroll
            for (int i = 0; i < 4; i++) mt[i] = fmaxf(mt[i], __shfl_xor(mt[i], off));
        }
#pragma unroll
        for (int i = 0; i < 4; i++) {
            const float mn = fmaxf(m[i], mt[i]);
            alpha[i] = expf(m[i] - mn);
            m[i] = mn;
            rs[i] = 0.0f;
        }
#pragma unroll
        for (int i = 0; i < 4; i++) {
#pragma unroll
            for (int j = 0; j < 2; j++) {
                const float p = expf(sc[i][j] - m[i]);
                sc[i][j] = p;
                rs[i] += p;
            }
        }
#pragma unroll
        for (int off = 1; off < 16; off <<= 1) {
#pragma unroll
            for (int i = 0; i < 4; i++) rs[i] += __shfl_xor(rs[i], off);
        }
#pragma unroll
        for (int i = 0; i < 4; i++) {
            l[i] = l[i] * alpha[i] + rs[i];
            ps[ty * 4 + i][tx * 2 + 0] = sc[i][0];
            ps[ty * 4 + i][tx * 2 + 1] = sc[i][1];
#pragma unroll
            for (int j = 0; j < 8; j++) o[i][j] *= alpha[i];
        }
        __syncthreads();
#pragma unroll 4
        for (int kk = 0; kk < 32; kk++) {
            float vv[8];
#pragma unroll
            for (int j = 0; j < 8; j++) vv[j] = vs[kk][tx * 8 + j];
#pragma unroll
            for (int i = 0; i < 4; i++) {
                const float p = ps[ty * 4 + i][kk];
#pragma unroll
                for (int j = 0; j < 8; j++) o[i][j] += p * vv[j];
            }
        }
    }
#pragma unroll
    for (int i = 0; i < 4; i++) {
        const int qg = q0 + ty * 4 + i;
        const float inv = 1.0f / l[i];
        float* dst = ctx + ((size_t)(b * cS + qg) * cH + h) * cDH + tx * 8;
        *(float4*)dst = make_float4(o[i][0] * inv, o[i][1] * inv, o[i][2] * inv, o[i][3] * inv);
        *(float4*)(dst + 4) = make_float4(o[i][4] * inv, o[i][5] * inv, o[i][6] * inv, o[i][7] * inv);
    }
}

// ---------------------------------------------------------------------------
// K6: O expert GEMM, bucketed. Block = (row tile, bucket (h,e), m-chunk z).
// out[bs,:] += w * (ctx[bs,h,:] @ Wo[h,e])  via atomicAdd.
// ---------------------------------------------------------------------------
__global__ __launch_bounds__(256) void k_oexp(
    const float* __restrict__ ctx, const float* __restrict__ Wo,
    const int* __restrict__ o_off, const int* __restrict__ o_cnt,
    const int* __restrict__ o_row, const float* __restrict__ o_wl,
    float* __restrict__ out)
{
    const int bkt = blockIdx.y;
    const int cnt = o_cnt[bkt];
    const int r0 = blockIdx.x * 64;
    if (r0 >= cnt) return;
    const int z = blockIdx.z;  // m chunk of 128
    const int n = min(64, cnt - r0);
    const int base = o_off[bkt] + r0;

    __shared__ int rows[64];
    __shared__ float rws[64];
    __shared__ float ct[64][132];
    __shared__ float wt[32][132];
    const int t = threadIdx.x, ty = t >> 4, tx = t & 15;
    if (t < 64) {
        rows[t] = o_row[base + min(t, n - 1)];
        rws[t] = (t < n) ? o_wl[base + t] : 0.0f;
    }
    __syncthreads();
    // ctx rows: row id rh = bs*H+h -> ctx + rh*DH (layout [B,S,H,DH])
    for (int i = t; i < 64 * 32; i += 256) {
        const int r = i >> 5, c = (i & 31) * 4;
        *(float4*)&ct[r][c] = *(const float4*)(ctx + (size_t)rows[r] * cDH + c);
    }
    const float* wbase = Wo + (size_t)bkt * cDH * cD + z * 128;
    float acc[4][8];
#pragma unroll
    for (int i = 0; i < 4; i++)
#pragma unroll
        for (int j = 0; j < 8; j++) acc[i][j] = 0.0f;

    for (int dc = 0; dc < cDH; dc += 32) {
        __syncthreads();
        for (int i = t; i < 32 * 32; i += 256) {
            const int r = i >> 5, c = (i & 31) * 4;
            *(float4*)&wt[r][c] = *(const float4*)(wbase + (size_t)(dc + r) * cD + c);
        }
        __syncthreads();
#pragma unroll 8
        for (int d = 0; d < 32; d++) {
            const float a0 = ct[ty * 4 + 0][dc + d], a1 = ct[ty * 4 + 1][dc + d];
            const float a2 = ct[ty * 4 + 2][dc + d], a3 = ct[ty * 4 + 3][dc + d];
#pragma unroll
            for (int j = 0; j < 8; j++) {
                const float bv = wt[d][tx * 8 + j];
                acc[0][j] += a0 * bv; acc[1][j] += a1 * bv;
                acc[2][j] += a2 * bv; acc[3][j] += a3 * bv;
            }
        }
    }
#pragma unroll
    for (int i = 0; i < 4; i++) {
        const int r = ty * 4 + i;
        if (r < n) {
            const int bs = rows[r] >> 3;
            const float w = rws[r];
            float* dst = out + (size_t)bs * cD + z * 128 + tx * 8;
#pragma unroll
            for (int j = 0; j < 8; j++) atomicAdd(&dst[j], w * acc[i][j]);
        }
    }
}

// ---------------------------------------------------------------------------
extern "C" void kernel_launch(void* const* d_in, const int* in_sizes, int n_in,
                              void* d_out, int out_size, void* d_ws, size_t ws_size,
                              hipStream_t stream)
{
    const float* x = (const float*)d_in[0];
    const float* Wq = (const float*)d_in[1];
    const float* Wk = (const float*)d_in[2];
    const float* Wv = (const float*)d_in[3];
    const float* Wo = (const float*)d_in[4];
    const float* sel_v = (const float*)d_in[5];
    const float* sel_o = (const float*)d_in[6];
    const int* positions = (const int*)d_in[7];
    float* out = (float*)d_out;

    char* ws = (char*)d_ws;
    size_t off = 0;
    auto alloc = [&](size_t bytes) -> void* {
        void* p = ws + off;
        off += (bytes + 255) & ~(size_t)255;
        return p;
    };
    const size_t big = (size_t)cB * cH * cS * cDH * sizeof(float);  // 32 MB
    float* q_t = (float*)alloc(big);
    float* k_t = (float*)alloc(big);
    float* v_t = (float*)alloc(big);
    float* ctx = (float*)alloc(big);
    float* vw = (float*)alloc((size_t)cNSEL * 4);
    int* vi = (int*)alloc((size_t)cNSEL * 4);
    float* ow = (float*)alloc((size_t)cNSEL * 4);
    int* oi = (int*)alloc((size_t)cNSEL * 4);
    int* meta = (int*)alloc(512 * 4);
    int* v_cnt = meta;            // 64
    int* o_cnt = meta + 64;       // 64
    int* v_off2 = meta + 128;     // 65
    int* o_off2 = meta + 193;     // 65
    int* v_cur = meta + 258;      // 64
    int* o_cur = meta + 322;      // 64
    int* v_row = (int*)alloc((size_t)cNSEL * 4);
    float* v_wl = (float*)alloc((size_t)cNSEL * 4);
    int* o_row = (int*)alloc((size_t)cNSEL * 4);
    float* o_wl = (float*)alloc((size_t)cNSEL * 4);

    hipMemsetAsync(v_t, 0, big, stream);
    hipMemsetAsync(out, 0, (size_t)cBS * cD * sizeof(float), stream);
    hipMemsetAsync(v_cnt, 0, 128 * sizeof(int), stream);

    k_gates<<<cBS / 8, 256, 0, stream>>>(x, sel_v, sel_o, vw, vi, ow, oi, v_cnt, o_cnt);
    k_prefix<<<1, 64, 0, stream>>>(v_cnt, o_cnt, v_off2, o_off2, v_cur, o_cur);
    k_scatter<<<2 * cNSEL / 256, 256, 0, stream>>>(vw, vi, ow, oi, v_off2, o_off2,
                                                   v_cur, o_cur, v_row, v_wl, o_row, o_wl);
    k_qkproj<<<dim3(cBS / 128, 16), 256, 0, stream>>>(x, Wq, Wk, q_t, k_t);
    k_rope<<<(2 * cB * cH * cS * (cDH / 2)) / 256, 256, 0, stream>>>(q_t, k_t, positions);
    k_vexp<<<dim3(96, cHE), 256, 0, stream>>>(x, Wv, v_off2, v_cnt, v_row, v_wl, v_t);
    k_attn<<<dim3(cS / 64, cH, cB), 256, 0, stream>>>(q_t, k_t, v_t, ctx);
    k_oexp<<<dim3(96, cHE, 8), 256, 0, stream>>>(ctx, Wo, o_off2, o_cnt, o_row, o_wl, out);
}

// Round 3
// 2607.655 us; speedup vs baseline: 2.7448x; 2.7448x over previous
//
#include <hip/hip_runtime.h>
#include <math.h>

typedef unsigned short u16;
typedef unsigned int u32;
typedef __attribute__((ext_vector_type(8))) short short8;  // 8 bf16 (4 VGPRs)
typedef __attribute__((ext_vector_type(4))) float f32x4;   // MFMA C/D

// Problem constants
constexpr int cB = 4, cS = 2048, cD = 1024, cH = 8, cE = 8, cK = 2, cDH = 128;
constexpr int cBS = cB * cS;          // 8192
constexpr int cHE = cH * cE;          // 64

__device__ inline u16 f2bf(float f) {
    u32 u = __float_as_uint(f);
    u += 0x7fffu + ((u >> 16) & 1u);   // RNE
    return (u16)(u >> 16);
}
__device__ inline float bf2f(u16 h) { return __uint_as_float(((u32)h) << 16); }

// ---------------------------------------------------------------------------
// K1: gates — per block: 8 rows of x; sigmoid(x @ sel^T) for v and o, top-2
// per (row,h), write DENSE gate arrays gv_d/go_d [8192][64] (0 if unselected).
// ---------------------------------------------------------------------------
__global__ __launch_bounds__(256) void k_gates(
    const float* __restrict__ x, const float* __restrict__ sel_v,
    const float* __restrict__ sel_o,
    float* __restrict__ gv_d, float* __restrict__ go_d)
{
    __shared__ float xs[8][cD];       // 32 KB
    __shared__ float gs[8][2 * cHE];  // 4 KB
    const int row0 = blockIdx.x * 8;
    const int t = threadIdx.x;

    const float4* xv = (const float4*)(x + (size_t)row0 * cD);
    float4* xsv = (float4*)&xs[0][0];
    for (int i = t; i < 8 * cD / 4; i += 256) xsv[i] = xv[i];
    __syncthreads();

    const int wave = t >> 6, lane = t & 63;
    for (int p = wave; p < 2 * cHE; p += 4) {
        const float* srow = (p < cHE) ? (sel_v + (size_t)p * cD)
                                      : (sel_o + (size_t)(p - cHE) * cD);
        float acc[8] = {0, 0, 0, 0, 0, 0, 0, 0};
        for (int d = lane; d < cD; d += 64) {
            float w = srow[d];
#pragma unroll
            for (int r = 0; r < 8; r++) acc[r] += w * xs[r][d];
        }
#pragma unroll
        for (int off = 32; off > 0; off >>= 1) {
#pragma unroll
            for (int r = 0; r < 8; r++) acc[r] += __shfl_down(acc[r], off);
        }
        if (lane == 0) {
            for (int r = 0; r < 8; r++) gs[r][p] = acc[r];
        }
    }
    __syncthreads();

    if (t < 128) {
        const int r = t >> 4, h = (t >> 1) & 7, which = t & 1;
        const float* g = &gs[r][which * cHE + h * cE];
        int i0 = 0; float b0 = g[0];
        for (int e = 1; e < cE; e++) { if (g[e] > b0) { b0 = g[e]; i0 = e; } }
        int i1 = -1; float b1 = -3.0e38f;
        for (int e = 0; e < cE; e++) { if (e != i0 && g[e] > b1) { b1 = g[e]; i1 = e; } }
        const float w0 = 1.0f / (1.0f + expf(-b0));
        const float w1 = 1.0f / (1.0f + expf(-b1));
        float* dst = (which ? go_d : gv_d) + (size_t)(row0 + r) * 64 + h * 8;
#pragma unroll
        for (int e = 0; e < cE; e++)
            dst[e] = (e == i0) ? w0 : ((e == i1) ? w1 : 0.0f);
    }
}

// ---------------------------------------------------------------------------
// Elementwise f32 -> bf16 cast (x and ctx; both 8192x1024). grid 8192 x 256.
// ---------------------------------------------------------------------------
__global__ __launch_bounds__(256) void k_cast_f2b(
    const float* __restrict__ src, u16* __restrict__ dst)
{
    const size_t i = (size_t)blockIdx.x * 256 + threadIdx.x;  // float4 index
    float4 v = ((const float4*)src)[i];
    u32 lo = (u32)f2bf(v.x) | ((u32)f2bf(v.y) << 16);
    u32 hi = (u32)f2bf(v.z) | ((u32)f2bf(v.w) << 16);
    uint2 o; o.x = lo; o.y = hi;
    ((uint2*)dst)[i] = o;
}

// ---------------------------------------------------------------------------
// Transpose-cast Wv [HE][D][DH] f32 -> WvT [(he*128+dh)][d] bf16.
// grid (16 d-tiles of 64, 64 he).
// ---------------------------------------------------------------------------
__global__ __launch_bounds__(256) void k_cast_wv(
    const float* __restrict__ Wv, u16* __restrict__ WvT)
{
    __shared__ float ld[64][132];  // [d-local][dh]
    const int d0 = blockIdx.x * 64, he = blockIdx.y;
    const int t = threadIdx.x;
    for (int p = 0; p < 8; p++) {
        const int slot = p * 256 + t, r = slot >> 5, c4 = slot & 31;
        float4 v = *(const float4*)(Wv + ((size_t)he * cD + d0 + r) * cDH + c4 * 4);
        ld[r][c4 * 4 + 0] = v.x; ld[r][c4 * 4 + 1] = v.y;
        ld[r][c4 * 4 + 2] = v.z; ld[r][c4 * 4 + 3] = v.w;
    }
    __syncthreads();
    for (int p = 0; p < 16; p++) {
        const int slot = p * 256 + t, dh = slot >> 5, c2 = slot & 31;
        u32 val = (u32)f2bf(ld[c2 * 2 + 0][dh]) | ((u32)f2bf(ld[c2 * 2 + 1][dh]) << 16);
        *(u32*)(WvT + (size_t)(he * cDH + dh) * cD + d0 + c2 * 2) = val;
    }
}

// ---------------------------------------------------------------------------
// Transpose-cast Wo [HE][DH][D] f32 -> WoT [m][(he*128+dh)] bf16.
// grid (16 m-tiles of 64, 64 he).
// ---------------------------------------------------------------------------
__global__ __launch_bounds__(256) void k_cast_wo(
    const float* __restrict__ Wo, u16* __restrict__ WoT)
{
    __shared__ float ld[128][68];  // [dh][m-local]
    const int m0 = blockIdx.x * 64, he = blockIdx.y;
    const int t = threadIdx.x;
    for (int p = 0; p < 8; p++) {
        const int slot = p * 256 + t, r = slot >> 4, c4 = slot & 15;
        float4 v = *(const float4*)(Wo + ((size_t)he * cDH + r) * cD + m0 + c4 * 4);
        ld[r][c4 * 4 + 0] = v.x; ld[r][c4 * 4 + 1] = v.y;
        ld[r][c4 * 4 + 2] = v.z; ld[r][c4 * 4 + 3] = v.w;
    }
    __syncthreads();
    for (int p = 0; p < 16; p++) {
        const int slot = p * 256 + t, mr = slot >> 6, c2 = slot & 63;
        u32 val = (u32)f2bf(ld[c2 * 2 + 0][mr]) | ((u32)f2bf(ld[c2 * 2 + 1][mr]) << 16);
        *(u32*)(WoT + (size_t)(m0 + mr) * 8192 + he * cDH + c2 * 2) = val;
    }
}

// ---------------------------------------------------------------------------
// K-GEMM-V: v_t[b,h,s,:] = sum_e gv[bs,h,e] * (x[bs,:] @ Wv[h,e])
// MFMA bf16 GEMM, M=128 tile, N=128(=DH), virtual K = (e,d) = 8192.
// Gate folded into A during LDS staging -> no atomics. grid (64, 8=h).
// ---------------------------------------------------------------------------
__global__ __launch_bounds__(256, 2) void k_gemm_v(
    const u16* __restrict__ xh, const u16* __restrict__ WvT,
    const float* __restrict__ gv_d, float* __restrict__ v_t)
{
    __shared__ u16 As[128 * 72];
    __shared__ u16 Bs[128 * 72];
    const int rt = blockIdx.x, h = blockIdx.y;
    const int r0 = rt * 128;
    const int t = threadIdx.x;
    const int w = t >> 6, lane = t & 63;
    const int wm = w >> 1, wn = w & 1;
    const int quad = lane >> 4, lm = lane & 15;

    f32x4 acc[4][4];
#pragma unroll
    for (int i = 0; i < 4; i++)
#pragma unroll
        for (int j = 0; j < 4; j++)
#pragma unroll
            for (int r = 0; r < 4; r++) acc[i][j][r] = 0.0f;

    for (int c = 0; c < 128; ++c) {
        const int e = c >> 4, kc = (c & 15) * 64;
        // A staging (gated): x column is e-independent (e replicates x)
#pragma unroll
        for (int p = 0; p < 4; p++) {
            const int slot = p * 256 + t, row = slot >> 3, seg = slot & 7;
            const float g = gv_d[(size_t)(r0 + row) * 64 + h * 8 + e];
            uint4 raw = *(const uint4*)(xh + (size_t)(r0 + row) * cD + kc + seg * 8);
            uint4 o;
            o.x = (u32)f2bf(bf2f((u16)(raw.x & 0xffff)) * g) |
                  ((u32)f2bf(bf2f((u16)(raw.x >> 16)) * g) << 16);
            o.y = (u32)f2bf(bf2f((u16)(raw.y & 0xffff)) * g) |
                  ((u32)f2bf(bf2f((u16)(raw.y >> 16)) * g) << 16);
            o.z = (u32)f2bf(bf2f((u16)(raw.z & 0xffff)) * g) |
                  ((u32)f2bf(bf2f((u16)(raw.z >> 16)) * g) << 16);
            o.w = (u32)f2bf(bf2f((u16)(raw.w & 0xffff)) * g) |
                  ((u32)f2bf(bf2f((u16)(raw.w >> 16)) * g) << 16);
            *(uint4*)(As + row * 72 + seg * 8) = o;
        }
        // B staging: WvT rows (h*8+e)*128 .. +127, cols kc..kc+63
#pragma unroll
        for (int p = 0; p < 4; p++) {
            const int slot = p * 256 + t, row = slot >> 3, seg = slot & 7;
            *(uint4*)(Bs + row * 72 + seg * 8) =
                *(const uint4*)(WvT + (size_t)((h * 8 + e) * cDH + row) * cD + kc + seg * 8);
        }
        __syncthreads();
#pragma unroll
        for (int ks = 0; ks < 64; ks += 32) {
            short8 av[4], bv[4];
#pragma unroll
            for (int i = 0; i < 4; i++)
                av[i] = *(const short8*)(As + (wm * 64 + i * 16 + lm) * 72 + ks + quad * 8);
#pragma unroll
            for (int j = 0; j < 4; j++)
                bv[j] = *(const short8*)(Bs + (wn * 64 + j * 16 + lm) * 72 + ks + quad * 8);
#pragma unroll
            for (int i = 0; i < 4; i++)
#pragma unroll
                for (int j = 0; j < 4; j++)
                    acc[i][j] = __builtin_amdgcn_mfma_f32_16x16x32_bf16(av[i], bv[j], acc[i][j], 0, 0, 0);
        }
        __syncthreads();
    }
#pragma unroll
    for (int i = 0; i < 4; i++) {
#pragma unroll
        for (int r = 0; r < 4; r++) {
            const int row = r0 + wm * 64 + i * 16 + quad * 4 + r;
            const int b = row >> 11, s = row & (cS - 1);
            float* dst = v_t + ((size_t)(b * cH + h) * cS + s) * cDH;
#pragma unroll
            for (int j = 0; j < 4; j++) {
                const int col = wn * 64 + j * 16 + lm;
                dst[col] = acc[i][j][r];
            }
        }
    }
}

// ---------------------------------------------------------------------------
// K-GEMM-O: out[bs,:] = sum_{h,e} go[bs,h,e] * (ctx[bs,h,:] @ Wo[h,e])
// MFMA bf16 GEMM, M=128 x N=128 tiles, K = (h,e,dh) = 8192, gate folded into
// A staging. Direct f32 stores (no atomics). grid (64 row-tiles, 8 n-tiles).
// NOTE: A is virtual over e — physical ctx column is h*128+dh, NOT k.
// ---------------------------------------------------------------------------
__global__ __launch_bounds__(256, 2) void k_gemm_o(
    const u16* __restrict__ ctxh, const u16* __restrict__ WoT,
    const float* __restrict__ go_d, float* __restrict__ out)
{
    __shared__ u16 As[128 * 72];
    __shared__ u16 Bs[128 * 72];
    const int rt = blockIdx.x, nt = blockIdx.y;
    const int r0 = rt * 128;
    const int t = threadIdx.x;
    const int w = t >> 6, lane = t & 63;
    const int wm = w >> 1, wn = w & 1;
    const int quad = lane >> 4, lm = lane & 15;

    f32x4 acc[4][4];
#pragma unroll
    for (int i = 0; i < 4; i++)
#pragma unroll
        for (int j = 0; j < 4; j++)
#pragma unroll
            for (int r = 0; r < 4; r++) acc[i][j][r] = 0.0f;

    for (int c = 0; c < 128; ++c) {
        const int he = c >> 1;
        // Physical ctx column for k = c*64+j: h*128 + dh, h=c>>4, dh=(c&1)*64+j
        const int ccol = (c >> 4) * 128 + (c & 1) * 64;   // BUGFIX (was c*64)
        // A staging (gated)
#pragma unroll
        for (int p = 0; p < 4; p++) {
            const int slot = p * 256 + t, row = slot >> 3, seg = slot & 7;
            const float g = go_d[(size_t)(r0 + row) * 64 + he];
            uint4 raw = *(const uint4*)(ctxh + (size_t)(r0 + row) * cD + ccol + seg * 8);
            uint4 o;
            o.x = (u32)f2bf(bf2f((u16)(raw.x & 0xffff)) * g) |
                  ((u32)f2bf(bf2f((u16)(raw.x >> 16)) * g) << 16);
            o.y = (u32)f2bf(bf2f((u16)(raw.y & 0xffff)) * g) |
                  ((u32)f2bf(bf2f((u16)(raw.y >> 16)) * g) << 16);
            o.z = (u32)f2bf(bf2f((u16)(raw.z & 0xffff)) * g) |
                  ((u32)f2bf(bf2f((u16)(raw.z >> 16)) * g) << 16);
            o.w = (u32)f2bf(bf2f((u16)(raw.w & 0xffff)) * g) |
                  ((u32)f2bf(bf2f((u16)(raw.w >> 16)) * g) << 16);
            *(uint4*)(As + row * 72 + seg * 8) = o;
        }
        // B staging: WoT rows nt*128 .. +127, k-cols c*64..+63
#pragma unroll
        for (int p = 0; p < 4; p++) {
            const int slot = p * 256 + t, row = slot >> 3, seg = slot & 7;
            *(uint4*)(Bs + row * 72 + seg * 8) =
                *(const uint4*)(WoT + (size_t)(nt * 128 + row) * 8192 + c * 64 + seg * 8);
        }
        __syncthreads();
#pragma unroll
        for (int ks = 0; ks < 64; ks += 32) {
            short8 av[4], bv[4];
#pragma unroll
            for (int i = 0; i < 4; i++)
                av[i] = *(const short8*)(As + (wm * 64 + i * 16 + lm) * 72 + ks + quad * 8);
#pragma unroll
            for (int j = 0; j < 4; j++)
                bv[j] = *(const short8*)(Bs + (wn * 64 + j * 16 + lm) * 72 + ks + quad * 8);
#pragma unroll
            for (int i = 0; i < 4; i++)
#pragma unroll
                for (int j = 0; j < 4; j++)
                    acc[i][j] = __builtin_amdgcn_mfma_f32_16x16x32_bf16(av[i], bv[j], acc[i][j], 0, 0, 0);
        }
        __syncthreads();
    }
#pragma unroll
    for (int i = 0; i < 4; i++) {
#pragma unroll
        for (int r = 0; r < 4; r++) {
            const int row = r0 + wm * 64 + i * 16 + quad * 4 + r;
            float* dst = out + (size_t)row * cD + nt * 128;
#pragma unroll
            for (int j = 0; j < 4; j++) {
                const int col = wn * 64 + j * 16 + lm;
                dst[col] = acc[i][j][r];
            }
        }
    }
}

// ---------------------------------------------------------------------------
// K4: Q/K projection (f32, unchanged).
// ---------------------------------------------------------------------------
__global__ __launch_bounds__(256) void k_qkproj(
    const float* __restrict__ x, const float* __restrict__ Wq,
    const float* __restrict__ Wk, float* __restrict__ q_t, float* __restrict__ k_t)
{
    const int rt = blockIdx.x;
    const int nt = blockIdx.y;
    const bool isK = nt >= cH;
    const int h = isK ? nt - cH : nt;
    const float* W = (isK ? Wk : Wq) + (size_t)h * cDH * cD;
    float* outp = isK ? k_t : q_t;

    __shared__ float at[128][17];
    __shared__ float bt[128][17];
    const int t = threadIdx.x, ty = t >> 4, tx = t & 15;

    float acc[8][8];
#pragma unroll
    for (int i = 0; i < 8; i++)
#pragma unroll
        for (int j = 0; j < 8; j++) acc[i][j] = 0.0f;

    const int r0 = rt * 128;
    const int lr = t >> 1, lc = (t & 1) * 8;
    for (int kc = 0; kc < cD; kc += 16) {
        const float* ap = x + (size_t)(r0 + lr) * cD + kc + lc;
        float4 a0 = *(const float4*)ap;
        float4 a1 = *(const float4*)(ap + 4);
        at[lr][lc + 0] = a0.x; at[lr][lc + 1] = a0.y; at[lr][lc + 2] = a0.z; at[lr][lc + 3] = a0.w;
        at[lr][lc + 4] = a1.x; at[lr][lc + 5] = a1.y; at[lr][lc + 6] = a1.z; at[lr][lc + 7] = a1.w;
        const float* bp = W + (size_t)lr * cD + kc + lc;
        float4 b0 = *(const float4*)bp;
        float4 b1 = *(const float4*)(bp + 4);
        bt[lr][lc + 0] = b0.x; bt[lr][lc + 1] = b0.y; bt[lr][lc + 2] = b0.z; bt[lr][lc + 3] = b0.w;
        bt[lr][lc + 4] = b1.x; bt[lr][lc + 5] = b1.y; bt[lr][lc + 6] = b1.z; bt[lr][lc + 7] = b1.w;
        __syncthreads();
#pragma unroll 4
        for (int d = 0; d < 16; d++) {
            float av[8], bv[8];
#pragma unroll
            for (int i = 0; i < 8; i++) av[i] = at[ty * 8 + i][d];
#pragma unroll
            for (int j = 0; j < 8; j++) bv[j] = bt[tx * 8 + j][d];
#pragma unroll
            for (int i = 0; i < 8; i++)
#pragma unroll
                for (int j = 0; j < 8; j++) acc[i][j] += av[i] * bv[j];
        }
        __syncthreads();
    }
#pragma unroll
    for (int i = 0; i < 8; i++) {
        const int r = r0 + ty * 8 + i;
        const int b = r >> 11, s = r & (cS - 1);
        float* dst = outp + ((size_t)(b * cH + h) * cS + s) * cDH + tx * 8;
        *(float4*)dst = make_float4(acc[i][0], acc[i][1], acc[i][2], acc[i][3]);
        *(float4*)(dst + 4) = make_float4(acc[i][4], acc[i][5], acc[i][6], acc[i][7]);
    }
}

// ---------------------------------------------------------------------------
// K4b: RoPE (f32, unchanged).
// ---------------------------------------------------------------------------
__global__ __launch_bounds__(256) void k_rope(
    float* __restrict__ q_t, float* __restrict__ k_t,
    const int* __restrict__ positions)
{
    const int total = cB * cH * cS * (cDH / 2);
    const int idx = blockIdx.x * 256 + threadIdx.x;
    const int which = (idx >= total) ? 1 : 0;
    const int id = which ? idx - total : idx;
    const int i = id & 63;
    const int bhs = id >> 6;
    const int s = bhs & (cS - 1);
    const int b = (bhs >> 11) >> 3;
    float* base = (which ? k_t : q_t) + (size_t)bhs * cDH;
    const int pos = positions[b * cS + s];
    const float freq = powf(10000.0f, -(float)i / 64.0f);
    const float ang = (float)pos * freq;
    const float c = cosf(ang), sn = sinf(ang);
    const float t1 = base[i], t2 = base[i + 64];
    base[i] = t1 * c - t2 * sn;
    base[i + 64] = t2 * c + t1 * sn;
}

// ---------------------------------------------------------------------------
// K5: causal flash attention (f32, unchanged).
// ---------------------------------------------------------------------------
__global__ __launch_bounds__(256) void k_attn(
    const float* __restrict__ q_t, const float* __restrict__ k_t,
    const float* __restrict__ v_t, float* __restrict__ ctx)
{
    const int qt = blockIdx.x, h = blockIdx.y, b = blockIdx.z;
    __shared__ float qs[64][132];
    __shared__ float ks[32][132];
    __shared__ float vs[32][132];
    __shared__ float ps[64][33];
    const int t = threadIdx.x, ty = t >> 4, tx = t & 15;
    const size_t hb = (size_t)(b * cH + h) * cS;
    const float* qbase = q_t + hb * cDH;
    const float* kbase = k_t + hb * cDH;
    const float* vbase = v_t + hb * cDH;
    const int q0 = qt * 64;

    for (int i = t; i < 64 * 32; i += 256) {
        const int r = i >> 5, c = (i & 31) * 4;
        *(float4*)&qs[r][c] = *(const float4*)(qbase + (size_t)(q0 + r) * cDH + c);
    }

    float m[4], l[4], o[4][8];
#pragma unroll
    for (int i = 0; i < 4; i++) {
        m[i] = -1.0e30f; l[i] = 0.0f;
#pragma unroll
        for (int j = 0; j < 8; j++) o[i][j] = 0.0f;
    }
    const float scale = 0.08838834764831845f;
    const int nkt = qt * 2 + 2;

    for (int kt = 0; kt < nkt; kt++) {
        const int k0 = kt * 32;
        __syncthreads();
        for (int i = t; i < 32 * 32; i += 256) {
            const int r = i >> 5, c = (i & 31) * 4;
            *(float4*)&ks[r][c] = *(const float4*)(kbase + (size_t)(k0 + r) * cDH + c);
            *(float4*)&vs[r][c] = *(const float4*)(vbase + (size_t)(k0 + r) * cDH + c);
        }
        __syncthreads();

        float sc[4][2];
#pragma unroll
        for (int i = 0; i < 4; i++) { sc[i][0] = 0.0f; sc[i][1] = 0.0f; }
#pragma unroll 4
        for (int d = 0; d < cDH; d++) {
            const float k0v = ks[tx * 2 + 0][d];
            const float k1v = ks[tx * 2 + 1][d];
#pragma unroll
            for (int i = 0; i < 4; i++) {
                const float qv = qs[ty * 4 + i][d];
                sc[i][0] += qv * k0v;
                sc[i][1] += qv * k1v;
            }
        }
#pragma unroll
        for (int i = 0; i < 4; i++) {
            const int qg = q0 + ty * 4 + i;
#pragma unroll
            for (int j = 0; j < 2; j++) {
                const int kg = k0 + tx * 2 + j;
                sc[i][j] = (kg <= qg) ? sc[i][j] * scale : -1.0e30f;
            }
        }
        float mt[4], alpha[4], rs[4];
#pragma unroll
        for (int i = 0; i < 4; i++) mt[i] = fmaxf(sc[i][0], sc[i][1]);
#pragma unroll
        for (int off = 1; off < 16; off <<= 1) {
#pragma unroll
            for (int i = 0; i < 4; i++) mt[i] = fmaxf(mt[i], __shfl_xor(mt[i], off));
        }
#pragma unroll
        for (int i = 0; i < 4; i++) {
            const float mn = fmaxf(m[i], mt[i]);
            alpha[i] = expf(m[i] - mn);
            m[i] = mn;
            rs[i] = 0.0f;
        }
#pragma unroll
        for (int i = 0; i < 4; i++) {
#pragma unroll
            for (int j = 0; j < 2; j++) {
                const float p = expf(sc[i][j] - m[i]);
                sc[i][j] = p;
                rs[i] += p;
            }
        }
#pragma unroll
        for (int off = 1; off < 16; off <<= 1) {
#pragma unroll
            for (int i = 0; i < 4; i++) rs[i] += __shfl_xor(rs[i], off);
        }
#pragma unroll
        for (int i = 0; i < 4; i++) {
            l[i] = l[i] * alpha[i] + rs[i];
            ps[ty * 4 + i][tx * 2 + 0] = sc[i][0];
            ps[ty * 4 + i][tx * 2 + 1] = sc[i][1];
#pragma unroll
            for (int j = 0; j < 8; j++) o[i][j] *= alpha[i];
        }
        __syncthreads();
#pragma unroll 4
        for (int kk = 0; kk < 32; kk++) {
            float vv[8];
#pragma unroll
            for (int j = 0; j < 8; j++) vv[j] = vs[kk][tx * 8 + j];
#pragma unroll
            for (int i = 0; i < 4; i++) {
                const float p = ps[ty * 4 + i][kk];
#pragma unroll
                for (int j = 0; j < 8; j++) o[i][j] += p * vv[j];
            }
        }
    }
#pragma unroll
    for (int i = 0; i < 4; i++) {
        const int qg = q0 + ty * 4 + i;
        const float inv = 1.0f / l[i];
        float* dst = ctx + ((size_t)(b * cS + qg) * cH + h) * cDH + tx * 8;
        *(float4*)dst = make_float4(o[i][0] * inv, o[i][1] * inv, o[i][2] * inv, o[i][3] * inv);
        *(float4*)(dst + 4) = make_float4(o[i][4] * inv, o[i][5] * inv, o[i][6] * inv, o[i][7] * inv);
    }
}

// ---------------------------------------------------------------------------
extern "C" void kernel_launch(void* const* d_in, const int* in_sizes, int n_in,
                              void* d_out, int out_size, void* d_ws, size_t ws_size,
                              hipStream_t stream)
{
    const float* x = (const float*)d_in[0];
    const float* Wq = (const float*)d_in[1];
    const float* Wk = (const float*)d_in[2];
    const float* Wv = (const float*)d_in[3];
    const float* Wo = (const float*)d_in[4];
    const float* sel_v = (const float*)d_in[5];
    const float* sel_o = (const float*)d_in[6];
    const int* positions = (const int*)d_in[7];
    float* out = (float*)d_out;

    char* ws = (char*)d_ws;
    size_t off = 0;
    auto alloc = [&](size_t bytes) -> void* {
        void* p = ws + off;
        off += (bytes + 255) & ~(size_t)255;
        return p;
    };
    const size_t big = (size_t)cB * cH * cS * cDH * sizeof(float);  // 32 MB
    // Region overlays (stream-ordered lifetimes):
    //   R1: WvT (bf16, phase 1) -> q_t (f32, phase 2) -> ctxh (bf16, phase 3)
    //   R2: k_t (f32, phase 2) -> WoT (bf16, phase 3)
    //   R3: v_t (f32)
    //   R4: xh (bf16, phase 1) -> ctx (f32, phase 3)
    char* R1 = (char*)alloc(big);
    char* R2 = (char*)alloc(big);
    char* R3 = (char*)alloc(big);
    char* R4 = (char*)alloc(big);
    float* gv_d = (float*)alloc((size_t)cBS * 64 * sizeof(float));  // 2 MB
    float* go_d = (float*)alloc((size_t)cBS * 64 * sizeof(float));  // 2 MB

    u16* WvT = (u16*)R1;
    float* q_t = (float*)R1;
    u16* ctxh = (u16*)R1;
    float* k_t = (float*)R2;
    u16* WoT = (u16*)R2;
    float* v_t = (float*)R3;
    u16* xh = (u16*)R4;
    float* ctx = (float*)R4;

    // Phase 1: gates, casts, V-expert GEMM
    k_gates<<<cBS / 8, 256, 0, stream>>>(x, sel_v, sel_o, gv_d, go_d);
    k_cast_f2b<<<8192, 256, 0, stream>>>(x, xh);
    k_cast_wv<<<dim3(16, 64), 256, 0, stream>>>(Wv, WvT);
    k_gemm_v<<<dim3(64, 8), 256, 0, stream>>>(xh, WvT, gv_d, v_t);

    // Phase 2: Q/K projection + RoPE + attention (f32)
    k_qkproj<<<dim3(cBS / 128, 16), 256, 0, stream>>>(x, Wq, Wk, q_t, k_t);
    k_rope<<<(2 * cB * cH * cS * (cDH / 2)) / 256, 256, 0, stream>>>(q_t, k_t, positions);
    k_attn<<<dim3(cS / 64, cH, cB), 256, 0, stream>>>(q_t, k_t, v_t, ctx);

    // Phase 3: O-expert GEMM (Wo cast reuses k_t region, ctxh reuses q_t)
    k_cast_wo<<<dim3(16, 64), 256, 0, stream>>>(Wo, WoT);
    k_cast_f2b<<<8192, 256, 0, stream>>>(ctx, ctxh);
    k_gemm_o<<<dim3(64, 8), 256, 0, stream>>>(ctxh, WoT, go_d, out);
}

// Round 4
// 1085.015 us; speedup vs baseline: 6.5966x; 2.4033x over previous
//
#include <hip/hip_runtime.h>
#include <math.h>

typedef unsigned short u16;
typedef unsigned int u32;
typedef __attribute__((ext_vector_type(8))) short short8;  // 8 bf16 (4 VGPRs)
typedef __attribute__((ext_vector_type(4))) float f32x4;   // MFMA C/D

// Problem constants
constexpr int cB = 4, cS = 2048, cD = 1024, cH = 8, cE = 8, cK = 2, cDH = 128;
constexpr int cBS = cB * cS;          // 8192
constexpr int cHE = cH * cE;          // 64

__device__ inline u16 f2bf(float f) {
    u32 u = __float_as_uint(f);
    u += 0x7fffu + ((u >> 16) & 1u);   // RNE
    return (u16)(u >> 16);
}
__device__ inline float bf2f(u16 h) { return __uint_as_float(((u32)h) << 16); }

// ---------------------------------------------------------------------------
// K1: gates — sigmoid(x @ sel^T), top-2 per (row,h); dense gate arrays.
// ---------------------------------------------------------------------------
__global__ __launch_bounds__(256) void k_gates(
    const float* __restrict__ x, const float* __restrict__ sel_v,
    const float* __restrict__ sel_o,
    float* __restrict__ gv_d, float* __restrict__ go_d)
{
    __shared__ float xs[8][cD];       // 32 KB
    __shared__ float gs[8][2 * cHE];  // 4 KB
    const int row0 = blockIdx.x * 8;
    const int t = threadIdx.x;

    const float4* xv = (const float4*)(x + (size_t)row0 * cD);
    float4* xsv = (float4*)&xs[0][0];
    for (int i = t; i < 8 * cD / 4; i += 256) xsv[i] = xv[i];
    __syncthreads();

    const int wave = t >> 6, lane = t & 63;
    for (int p = wave; p < 2 * cHE; p += 4) {
        const float* srow = (p < cHE) ? (sel_v + (size_t)p * cD)
                                      : (sel_o + (size_t)(p - cHE) * cD);
        float acc[8] = {0, 0, 0, 0, 0, 0, 0, 0};
        for (int d = lane; d < cD; d += 64) {
            float w = srow[d];
#pragma unroll
            for (int r = 0; r < 8; r++) acc[r] += w * xs[r][d];
        }
#pragma unroll
        for (int off = 32; off > 0; off >>= 1) {
#pragma unroll
            for (int r = 0; r < 8; r++) acc[r] += __shfl_down(acc[r], off);
        }
        if (lane == 0) {
            for (int r = 0; r < 8; r++) gs[r][p] = acc[r];
        }
    }
    __syncthreads();

    if (t < 128) {
        const int r = t >> 4, h = (t >> 1) & 7, which = t & 1;
        const float* g = &gs[r][which * cHE + h * cE];
        int i0 = 0; float b0 = g[0];
        for (int e = 1; e < cE; e++) { if (g[e] > b0) { b0 = g[e]; i0 = e; } }
        int i1 = -1; float b1 = -3.0e38f;
        for (int e = 0; e < cE; e++) { if (e != i0 && g[e] > b1) { b1 = g[e]; i1 = e; } }
        const float w0 = 1.0f / (1.0f + expf(-b0));
        const float w1 = 1.0f / (1.0f + expf(-b1));
        float* dst = (which ? go_d : gv_d) + (size_t)(row0 + r) * 64 + h * 8;
#pragma unroll
        for (int e = 0; e < cE; e++)
            dst[e] = (e == i0) ? w0 : ((e == i1) ? w1 : 0.0f);
    }
}

// ---------------------------------------------------------------------------
// Elementwise f32 -> bf16 cast. grid = n/1024 blocks x 256.
// ---------------------------------------------------------------------------
__global__ __launch_bounds__(256) void k_cast_f2b(
    const float* __restrict__ src, u16* __restrict__ dst)
{
    const size_t i = (size_t)blockIdx.x * 256 + threadIdx.x;  // float4 index
    float4 v = ((const float4*)src)[i];
    u32 lo = (u32)f2bf(v.x) | ((u32)f2bf(v.y) << 16);
    u32 hi = (u32)f2bf(v.z) | ((u32)f2bf(v.w) << 16);
    uint2 o; o.x = lo; o.y = hi;
    ((uint2*)dst)[i] = o;
}

// ---------------------------------------------------------------------------
// Transpose-cast Wv [HE][D][DH] f32 -> WvT [(he*128+dh)][d] bf16.
// ---------------------------------------------------------------------------
__global__ __launch_bounds__(256) void k_cast_wv(
    const float* __restrict__ Wv, u16* __restrict__ WvT)
{
    __shared__ float ld[64][132];  // [d-local][dh]
    const int d0 = blockIdx.x * 64, he = blockIdx.y;
    const int t = threadIdx.x;
    for (int p = 0; p < 8; p++) {
        const int slot = p * 256 + t, r = slot >> 5, c4 = slot & 31;
        float4 v = *(const float4*)(Wv + ((size_t)he * cD + d0 + r) * cDH + c4 * 4);
        ld[r][c4 * 4 + 0] = v.x; ld[r][c4 * 4 + 1] = v.y;
        ld[r][c4 * 4 + 2] = v.z; ld[r][c4 * 4 + 3] = v.w;
    }
    __syncthreads();
    for (int p = 0; p < 16; p++) {
        const int slot = p * 256 + t, dh = slot >> 5, c2 = slot & 31;
        u32 val = (u32)f2bf(ld[c2 * 2 + 0][dh]) | ((u32)f2bf(ld[c2 * 2 + 1][dh]) << 16);
        *(u32*)(WvT + (size_t)(he * cDH + dh) * cD + d0 + c2 * 2) = val;
    }
}

// ---------------------------------------------------------------------------
// Transpose-cast Wo [HE][DH][D] f32 -> WoT [m][(he*128+dh)] bf16.
// ---------------------------------------------------------------------------
__global__ __launch_bounds__(256) void k_cast_wo(
    const float* __restrict__ Wo, u16* __restrict__ WoT)
{
    __shared__ float ld[128][68];  // [dh][m-local]
    const int m0 = blockIdx.x * 64, he = blockIdx.y;
    const int t = threadIdx.x;
    for (int p = 0; p < 8; p++) {
        const int slot = p * 256 + t, r = slot >> 4, c4 = slot & 15;
        float4 v = *(const float4*)(Wo + ((size_t)he * cDH + r) * cD + m0 + c4 * 4);
        ld[r][c4 * 4 + 0] = v.x; ld[r][c4 * 4 + 1] = v.y;
        ld[r][c4 * 4 + 2] = v.z; ld[r][c4 * 4 + 3] = v.w;
    }
    __syncthreads();
    for (int p = 0; p < 16; p++) {
        const int slot = p * 256 + t, mr = slot >> 6, c2 = slot & 63;
        u32 val = (u32)f2bf(ld[c2 * 2 + 0][mr]) | ((u32)f2bf(ld[c2 * 2 + 1][mr]) << 16);
        *(u32*)(WoT + (size_t)(m0 + mr) * 8192 + he * cDH + c2 * 2) = val;
    }
}

// ---------------------------------------------------------------------------
// K-GEMM-V: v_b[b,h,s,:] = sum_e gv[bs,h,e] * (x[bs,:] @ Wv[h,e])  (bf16 out)
// ---------------------------------------------------------------------------
__global__ __launch_bounds__(256, 2) void k_gemm_v(
    const u16* __restrict__ xh, const u16* __restrict__ WvT,
    const float* __restrict__ gv_d, u16* __restrict__ v_b)
{
    __shared__ u16 As[128 * 72];
    __shared__ u16 Bs[128 * 72];
    const int rt = blockIdx.x, h = blockIdx.y;
    const int r0 = rt * 128;
    const int t = threadIdx.x;
    const int w = t >> 6, lane = t & 63;
    const int wm = w >> 1, wn = w & 1;
    const int quad = lane >> 4, lm = lane & 15;

    f32x4 acc[4][4];
#pragma unroll
    for (int i = 0; i < 4; i++)
#pragma unroll
        for (int j = 0; j < 4; j++)
#pragma unroll
            for (int r = 0; r < 4; r++) acc[i][j][r] = 0.0f;

    for (int c = 0; c < 128; ++c) {
        const int e = c >> 4, kc = (c & 15) * 64;
#pragma unroll
        for (int p = 0; p < 4; p++) {
            const int slot = p * 256 + t, row = slot >> 3, seg = slot & 7;
            const float g = gv_d[(size_t)(r0 + row) * 64 + h * 8 + e];
            uint4 raw = *(const uint4*)(xh + (size_t)(r0 + row) * cD + kc + seg * 8);
            uint4 o;
            o.x = (u32)f2bf(bf2f((u16)(raw.x & 0xffff)) * g) |
                  ((u32)f2bf(bf2f((u16)(raw.x >> 16)) * g) << 16);
            o.y = (u32)f2bf(bf2f((u16)(raw.y & 0xffff)) * g) |
                  ((u32)f2bf(bf2f((u16)(raw.y >> 16)) * g) << 16);
            o.z = (u32)f2bf(bf2f((u16)(raw.z & 0xffff)) * g) |
                  ((u32)f2bf(bf2f((u16)(raw.z >> 16)) * g) << 16);
            o.w = (u32)f2bf(bf2f((u16)(raw.w & 0xffff)) * g) |
                  ((u32)f2bf(bf2f((u16)(raw.w >> 16)) * g) << 16);
            *(uint4*)(As + row * 72 + seg * 8) = o;
        }
#pragma unroll
        for (int p = 0; p < 4; p++) {
            const int slot = p * 256 + t, row = slot >> 3, seg = slot & 7;
            *(uint4*)(Bs + row * 72 + seg * 8) =
                *(const uint4*)(WvT + (size_t)((h * 8 + e) * cDH + row) * cD + kc + seg * 8);
        }
        __syncthreads();
#pragma unroll
        for (int ks = 0; ks < 64; ks += 32) {
            short8 av[4], bv[4];
#pragma unroll
            for (int i = 0; i < 4; i++)
                av[i] = *(const short8*)(As + (wm * 64 + i * 16 + lm) * 72 + ks + quad * 8);
#pragma unroll
            for (int j = 0; j < 4; j++)
                bv[j] = *(const short8*)(Bs + (wn * 64 + j * 16 + lm) * 72 + ks + quad * 8);
#pragma unroll
            for (int i = 0; i < 4; i++)
#pragma unroll
                for (int j = 0; j < 4; j++)
                    acc[i][j] = __builtin_amdgcn_mfma_f32_16x16x32_bf16(av[i], bv[j], acc[i][j], 0, 0, 0);
        }
        __syncthreads();
    }
#pragma unroll
    for (int i = 0; i < 4; i++) {
#pragma unroll
        for (int r = 0; r < 4; r++) {
            const int row = r0 + wm * 64 + i * 16 + quad * 4 + r;
            const int b = row >> 11, s = row & (cS - 1);
            u16* dst = v_b + ((size_t)(b * cH + h) * cS + s) * cDH;
#pragma unroll
            for (int j = 0; j < 4; j++) {
                const int col = wn * 64 + j * 16 + lm;
                dst[col] = f2bf(acc[i][j][r]);
            }
        }
    }
}

// ---------------------------------------------------------------------------
// K-GEMM-O: out[bs,:] = sum_{h,e} go[bs,h,e] * (ctx[bs,h,:] @ Wo[h,e])
// ---------------------------------------------------------------------------
__global__ __launch_bounds__(256, 2) void k_gemm_o(
    const u16* __restrict__ ctxh, const u16* __restrict__ WoT,
    const float* __restrict__ go_d, float* __restrict__ out)
{
    __shared__ u16 As[128 * 72];
    __shared__ u16 Bs[128 * 72];
    const int rt = blockIdx.x, nt = blockIdx.y;
    const int r0 = rt * 128;
    const int t = threadIdx.x;
    const int w = t >> 6, lane = t & 63;
    const int wm = w >> 1, wn = w & 1;
    const int quad = lane >> 4, lm = lane & 15;

    f32x4 acc[4][4];
#pragma unroll
    for (int i = 0; i < 4; i++)
#pragma unroll
        for (int j = 0; j < 4; j++)
#pragma unroll
            for (int r = 0; r < 4; r++) acc[i][j][r] = 0.0f;

    for (int c = 0; c < 128; ++c) {
        const int he = c >> 1;
        const int ccol = (c >> 4) * 128 + (c & 1) * 64;  // physical ctx column
#pragma unroll
        for (int p = 0; p < 4; p++) {
            const int slot = p * 256 + t, row = slot >> 3, seg = slot & 7;
            const float g = go_d[(size_t)(r0 + row) * 64 + he];
            uint4 raw = *(const uint4*)(ctxh + (size_t)(r0 + row) * cD + ccol + seg * 8);
            uint4 o;
            o.x = (u32)f2bf(bf2f((u16)(raw.x & 0xffff)) * g) |
                  ((u32)f2bf(bf2f((u16)(raw.x >> 16)) * g) << 16);
            o.y = (u32)f2bf(bf2f((u16)(raw.y & 0xffff)) * g) |
                  ((u32)f2bf(bf2f((u16)(raw.y >> 16)) * g) << 16);
            o.z = (u32)f2bf(bf2f((u16)(raw.z & 0xffff)) * g) |
                  ((u32)f2bf(bf2f((u16)(raw.z >> 16)) * g) << 16);
            o.w = (u32)f2bf(bf2f((u16)(raw.w & 0xffff)) * g) |
                  ((u32)f2bf(bf2f((u16)(raw.w >> 16)) * g) << 16);
            *(uint4*)(As + row * 72 + seg * 8) = o;
        }
#pragma unroll
        for (int p = 0; p < 4; p++) {
            const int slot = p * 256 + t, row = slot >> 3, seg = slot & 7;
            *(uint4*)(Bs + row * 72 + seg * 8) =
                *(const uint4*)(WoT + (size_t)(nt * 128 + row) * 8192 + c * 64 + seg * 8);
        }
        __syncthreads();
#pragma unroll
        for (int ks = 0; ks < 64; ks += 32) {
            short8 av[4], bv[4];
#pragma unroll
            for (int i = 0; i < 4; i++)
                av[i] = *(const short8*)(As + (wm * 64 + i * 16 + lm) * 72 + ks + quad * 8);
#pragma unroll
            for (int j = 0; j < 4; j++)
                bv[j] = *(const short8*)(Bs + (wn * 64 + j * 16 + lm) * 72 + ks + quad * 8);
#pragma unroll
            for (int i = 0; i < 4; i++)
#pragma unroll
                for (int j = 0; j < 4; j++)
                    acc[i][j] = __builtin_amdgcn_mfma_f32_16x16x32_bf16(av[i], bv[j], acc[i][j], 0, 0, 0);
        }
        __syncthreads();
    }
#pragma unroll
    for (int i = 0; i < 4; i++) {
#pragma unroll
        for (int r = 0; r < 4; r++) {
            const int row = r0 + wm * 64 + i * 16 + quad * 4 + r;
            float* dst = out + (size_t)row * cD + nt * 128;
#pragma unroll
            for (int j = 0; j < 4; j++) {
                const int col = wn * 64 + j * 16 + lm;
                dst[col] = acc[i][j][r];
            }
        }
    }
}

// ---------------------------------------------------------------------------
// K-QKPROJ (MFMA): q/k = x @ Wq^T / Wk^T per head. M=128-row tiles, N=128=DH,
// K=1024. B = Wq/Wk bf16 [h*128+dh][d] (already B^T layout). f32 out [b,h,s,dh].
// grid (64 row-tiles, 16: nt<8 Q head nt, else K head nt-8).
// ---------------------------------------------------------------------------
__global__ __launch_bounds__(256, 2) void k_qkproj_mfma(
    const u16* __restrict__ xh, const u16* __restrict__ Wqb,
    const u16* __restrict__ Wkb, float* __restrict__ q_t, float* __restrict__ k_t)
{
    __shared__ u16 As[128 * 72];
    __shared__ u16 Bs[128 * 72];
    const int rt = blockIdx.x, nt = blockIdx.y;
    const bool isK = nt >= cH;
    const int h = isK ? nt - cH : nt;
    const u16* Wb = isK ? Wkb : Wqb;
    float* outp = isK ? k_t : q_t;
    const int r0 = rt * 128;
    const int t = threadIdx.x;
    const int w = t >> 6, lane = t & 63;
    const int wm = w >> 1, wn = w & 1;
    const int quad = lane >> 4, lm = lane & 15;

    f32x4 acc[4][4];
#pragma unroll
    for (int i = 0; i < 4; i++)
#pragma unroll
        for (int j = 0; j < 4; j++)
#pragma unroll
            for (int r = 0; r < 4; r++) acc[i][j][r] = 0.0f;

    for (int kc = 0; kc < cD; kc += 64) {
#pragma unroll
        for (int p = 0; p < 4; p++) {
            const int slot = p * 256 + t, row = slot >> 3, seg = slot & 7;
            *(uint4*)(As + row * 72 + seg * 8) =
                *(const uint4*)(xh + (size_t)(r0 + row) * cD + kc + seg * 8);
        }
#pragma unroll
        for (int p = 0; p < 4; p++) {
            const int slot = p * 256 + t, row = slot >> 3, seg = slot & 7;
            *(uint4*)(Bs + row * 72 + seg * 8) =
                *(const uint4*)(Wb + (size_t)(h * cDH + row) * cD + kc + seg * 8);
        }
        __syncthreads();
#pragma unroll
        for (int ks = 0; ks < 64; ks += 32) {
            short8 av[4], bv[4];
#pragma unroll
            for (int i = 0; i < 4; i++)
                av[i] = *(const short8*)(As + (wm * 64 + i * 16 + lm) * 72 + ks + quad * 8);
#pragma unroll
            for (int j = 0; j < 4; j++)
                bv[j] = *(const short8*)(Bs + (wn * 64 + j * 16 + lm) * 72 + ks + quad * 8);
#pragma unroll
            for (int i = 0; i < 4; i++)
#pragma unroll
                for (int j = 0; j < 4; j++)
                    acc[i][j] = __builtin_amdgcn_mfma_f32_16x16x32_bf16(av[i], bv[j], acc[i][j], 0, 0, 0);
        }
        __syncthreads();
    }
#pragma unroll
    for (int i = 0; i < 4; i++) {
#pragma unroll
        for (int r = 0; r < 4; r++) {
            const int row = r0 + wm * 64 + i * 16 + quad * 4 + r;
            const int b = row >> 11, s = row & (cS - 1);
            float* dst = outp + ((size_t)(b * cH + h) * cS + s) * cDH;
#pragma unroll
            for (int j = 0; j < 4; j++) {
                const int col = wn * 64 + j * 16 + lm;
                dst[col] = acc[i][j][r];
            }
        }
    }
}

// ---------------------------------------------------------------------------
// RoPE + cast: read f32 q_t/k_t [b,h,s,dh], write bf16 q_b/k_b same layout.
// ---------------------------------------------------------------------------
__global__ __launch_bounds__(256) void k_rope_cast(
    const float* __restrict__ q_t, const float* __restrict__ k_t,
    const int* __restrict__ positions,
    u16* __restrict__ q_b, u16* __restrict__ k_b)
{
    const int total = cB * cH * cS * (cDH / 2);
    const int idx = blockIdx.x * 256 + threadIdx.x;
    const int which = (idx >= total) ? 1 : 0;
    const int id = which ? idx - total : idx;
    const int i = id & 63;
    const int bhs = id >> 6;
    const int s = bhs & (cS - 1);
    const int b = (bhs >> 11) >> 3;
    const float* src = (which ? k_t : q_t) + (size_t)bhs * cDH;
    u16* dst = (which ? k_b : q_b) + (size_t)bhs * cDH;
    const int pos = positions[b * cS + s];
    const float freq = powf(10000.0f, -(float)i / 64.0f);
    const float ang = (float)pos * freq;
    const float c = cosf(ang), sn = sinf(ang);
    const float t1 = src[i], t2 = src[i + 64];
    dst[i] = f2bf(t1 * c - t2 * sn);
    dst[i + 64] = f2bf(t2 * c + t1 * sn);
}

// ---------------------------------------------------------------------------
// K5: MFMA flash attention. BQ=64 (4 waves x 16 rows), BK=64, DH=128.
// Inputs bf16 [b,h,s,dh]; output ctxh bf16 [b,s,h,dh].
// grid (32 q-tiles reversed, 8 h, 4 b).
// ---------------------------------------------------------------------------
__global__ __launch_bounds__(256, 3) void k_attn_mfma(
    const u16* __restrict__ qb, const u16* __restrict__ kb,
    const u16* __restrict__ vb, u16* __restrict__ ctxh)
{
    __shared__ u16 Ks[64][136];    // [kv][dh], 17.4 KB
    __shared__ u16 VsT[128][72];   // [dh][kv], 18.4 KB
    __shared__ u16 Ps[4][16][72];  // per-wave P strip [qrow][kv], 9.2 KB

    const int qt = (int)gridDim.x - 1 - (int)blockIdx.x;  // heavy tiles first
    const int h = blockIdx.y, b = blockIdx.z;
    const int q0 = qt * 64;
    const int t = threadIdx.x;
    const int w = t >> 6, lane = t & 63;
    const int quad = lane >> 4, lm = lane & 15;
    const size_t bh = (size_t)(b * cH + h) * cS;
    const u16* kbase = kb + bh * cDH;
    const u16* vbase = vb + bh * cDH;

    // Q fragments (register-resident): wave w owns rows q0+w*16 .. +15
    const u16* qrow = qb + (bh + q0 + w * 16 + lm) * cDH;
    short8 aq[4];
#pragma unroll
    for (int ks = 0; ks < 4; ks++)
        aq[ks] = *(const short8*)(qrow + ks * 32 + quad * 8);

    f32x4 o_acc[8];
#pragma unroll
    for (int j = 0; j < 8; j++)
#pragma unroll
        for (int r = 0; r < 4; r++) o_acc[j][r] = 0.0f;
    float m_r[4] = {-1.0e30f, -1.0e30f, -1.0e30f, -1.0e30f};
    float l_r[4] = {0.0f, 0.0f, 0.0f, 0.0f};
    const float scale = 0.08838834764831845f;  // 1/sqrt(128)

    for (int kt = 0; kt <= qt; kt++) {
        const int k0 = kt * 64;
        // stage K: 64 rows x 128 dh (uint4 = 8 bf16)
#pragma unroll
        for (int p = 0; p < 4; p++) {
            const int slot = p * 256 + t, row = slot >> 4, seg = slot & 15;
            *(uint4*)&Ks[row][seg * 8] =
                *(const uint4*)(kbase + (size_t)(k0 + row) * cDH + seg * 8);
        }
        // stage V transposed: thread = (rq = kv quad, seg = dh octet)
        {
            const int rq = t & 15, seg = t >> 4;
            uint4 r0v = *(const uint4*)(vbase + (size_t)(k0 + rq * 4 + 0) * cDH + seg * 8);
            uint4 r1v = *(const uint4*)(vbase + (size_t)(k0 + rq * 4 + 1) * cDH + seg * 8);
            uint4 r2v = *(const uint4*)(vbase + (size_t)(k0 + rq * 4 + 2) * cDH + seg * 8);
            uint4 r3v = *(const uint4*)(vbase + (size_t)(k0 + rq * 4 + 3) * cDH + seg * 8);
            const u16* p0 = (const u16*)&r0v; const u16* p1 = (const u16*)&r1v;
            const u16* p2 = (const u16*)&r2v; const u16* p3 = (const u16*)&r3v;
#pragma unroll
            for (int jj = 0; jj < 8; jj++) {
                ushort4 val;
                val.x = p0[jj]; val.y = p1[jj]; val.z = p2[jj]; val.w = p3[jj];
                *(ushort4*)&VsT[seg * 8 + jj][rq * 4] = val;
            }
        }
        __syncthreads();

        // QK^T: wave's 16 rows x 64 cols
        f32x4 s[4];
#pragma unroll
        for (int j = 0; j < 4; j++)
#pragma unroll
            for (int r = 0; r < 4; r++) s[j][r] = 0.0f;
#pragma unroll
        for (int ks = 0; ks < 4; ks++) {
#pragma unroll
            for (int j = 0; j < 4; j++) {
                short8 bv = *(const short8*)&Ks[j * 16 + lm][ks * 32 + quad * 8];
                s[j] = __builtin_amdgcn_mfma_f32_16x16x32_bf16(aq[ks], bv, s[j], 0, 0, 0);
            }
        }
        // scale + causal mask (only diagonal tile needs the mask)
        if (kt == qt) {
#pragma unroll
            for (int j = 0; j < 4; j++) {
                const int colg = k0 + j * 16 + lm;
#pragma unroll
                for (int r = 0; r < 4; r++) {
                    const int rowg = q0 + w * 16 + quad * 4 + r;
                    s[j][r] = (colg <= rowg) ? s[j][r] * scale : -1.0e30f;
                }
            }
        } else {
#pragma unroll
            for (int j = 0; j < 4; j++)
#pragma unroll
                for (int r = 0; r < 4; r++) s[j][r] *= scale;
        }
        // online softmax (row stats across the quad's 16 lanes)
        float mt[4];
#pragma unroll
        for (int r = 0; r < 4; r++)
            mt[r] = fmaxf(fmaxf(s[0][r], s[1][r]), fmaxf(s[2][r], s[3][r]));
#pragma unroll
        for (int off = 1; off < 16; off <<= 1)
#pragma unroll
            for (int r = 0; r < 4; r++) mt[r] = fmaxf(mt[r], __shfl_xor(mt[r], off));
        float alpha[4], rs[4];
#pragma unroll
        for (int r = 0; r < 4; r++) {
            const float mn = fmaxf(m_r[r], mt[r]);
            alpha[r] = __expf(m_r[r] - mn);
            m_r[r] = mn;
            rs[r] = 0.0f;
        }
#pragma unroll
        for (int j = 0; j < 4; j++)
#pragma unroll
            for (int r = 0; r < 4; r++) {
                const float p = __expf(s[j][r] - m_r[r]);
                s[j][r] = p;
                rs[r] += p;
            }
#pragma unroll
        for (int off = 1; off < 16; off <<= 1)
#pragma unroll
            for (int r = 0; r < 4; r++) rs[r] += __shfl_xor(rs[r], off);
#pragma unroll
        for (int r = 0; r < 4; r++) l_r[r] = l_r[r] * alpha[r] + rs[r];
#pragma unroll
        for (int j = 0; j < 8; j++)
#pragma unroll
            for (int r = 0; r < 4; r++) o_acc[j][r] *= alpha[r];
        // P -> LDS (wave-private strip), bf16
#pragma unroll
        for (int j = 0; j < 4; j++)
#pragma unroll
            for (int r = 0; r < 4; r++)
                Ps[w][quad * 4 + r][j * 16 + lm] = f2bf(s[j][r]);
        // PV: O[16 x 128] += P[16 x 64] * V[64 x 128]
#pragma unroll
        for (int ks2 = 0; ks2 < 2; ks2++) {
            short8 ap = *(const short8*)&Ps[w][lm][ks2 * 32 + quad * 8];
#pragma unroll
            for (int j2 = 0; j2 < 8; j2++) {
                short8 bv = *(const short8*)&VsT[j2 * 16 + lm][ks2 * 32 + quad * 8];
                o_acc[j2] = __builtin_amdgcn_mfma_f32_16x16x32_bf16(ap, bv, o_acc[j2], 0, 0, 0);
            }
        }
        __syncthreads();
    }
    // epilogue: ctxh [b,s,h,dh] bf16
#pragma unroll
    for (int r = 0; r < 4; r++) {
        const float inv = 1.0f / l_r[r];
        const int sg = q0 + w * 16 + quad * 4 + r;
        u16* dst = ctxh + (((size_t)b * cS + sg) * cH + h) * cDH;
#pragma unroll
        for (int j2 = 0; j2 < 8; j2++)
            dst[j2 * 16 + lm] = f2bf(o_acc[j2][r] * inv);
    }
}

// ---------------------------------------------------------------------------
extern "C" void kernel_launch(void* const* d_in, const int* in_sizes, int n_in,
                              void* d_out, int out_size, void* d_ws, size_t ws_size,
                              hipStream_t stream)
{
    const float* x = (const float*)d_in[0];
    const float* Wq = (const float*)d_in[1];
    const float* Wk = (const float*)d_in[2];
    const float* Wv = (const float*)d_in[3];
    const float* Wo = (const float*)d_in[4];
    const float* sel_v = (const float*)d_in[5];
    const float* sel_o = (const float*)d_in[6];
    const int* positions = (const int*)d_in[7];
    float* out = (float*)d_out;

    char* ws = (char*)d_ws;
    size_t off = 0;
    auto alloc = [&](size_t bytes) -> void* {
        void* p = ws + off;
        off += (bytes + 255) & ~(size_t)255;
        return p;
    };
    const size_t big = (size_t)cB * cH * cS * cDH * sizeof(float);  // 32 MB
    const size_t half = big / 2;                                    // 16 MB
    // Overlays (stream-ordered lifetimes):
    //   R1: WvT bf16 (ph1) -> q_t f32 (ph2)
    //   R2: k_t f32 (ph2) -> WoT bf16 (ph3)
    //   R3: [0,16M) v_b bf16 (ph1->attn); [16M,32M) Wqb+Wkb bf16 (->qkproj),
    //       then ctxh bf16 (attn->gemm_o)
    //   R4: [0,16M) xh bf16 (->qkproj) then q_b bf16; [16M,32M) k_b bf16
    char* R1 = (char*)alloc(big);
    char* R2 = (char*)alloc(big);
    char* R3 = (char*)alloc(big);
    char* R4 = (char*)alloc(big);
    float* gv_d = (float*)alloc((size_t)cBS * 64 * sizeof(float));  // 2 MB
    float* go_d = (float*)alloc((size_t)cBS * 64 * sizeof(float));  // 2 MB

    u16* WvT = (u16*)R1;
    float* q_t = (float*)R1;
    float* k_t = (float*)R2;
    u16* WoT = (u16*)R2;
    u16* v_b = (u16*)R3;
    u16* Wqb = (u16*)(R3 + half);
    u16* Wkb = (u16*)(R3 + half + ((size_t)cD * cD * 2));
    u16* ctxh = (u16*)(R3 + half);
    u16* xh = (u16*)R4;
    u16* q_b = (u16*)R4;
    u16* k_b = (u16*)(R4 + half);

    // Phase 1: gates, casts, V-expert GEMM
    k_gates<<<cBS / 8, 256, 0, stream>>>(x, sel_v, sel_o, gv_d, go_d);
    k_cast_f2b<<<8192, 256, 0, stream>>>(x, xh);
    k_cast_wv<<<dim3(16, 64), 256, 0, stream>>>(Wv, WvT);
    k_gemm_v<<<dim3(64, 8), 256, 0, stream>>>(xh, WvT, gv_d, v_b);

    // Phase 2: Q/K projection (MFMA) + RoPE-cast + MFMA attention
    k_cast_f2b<<<1024, 256, 0, stream>>>(Wq, Wqb);
    k_cast_f2b<<<1024, 256, 0, stream>>>(Wk, Wkb);
    k_qkproj_mfma<<<dim3(64, 16), 256, 0, stream>>>(xh, Wqb, Wkb, q_t, k_t);
    k_rope_cast<<<(2 * cB * cH * cS * (cDH / 2)) / 256, 256, 0, stream>>>(
        q_t, k_t, positions, q_b, k_b);
    k_attn_mfma<<<dim3(cS / 64, cH, cB), 256, 0, stream>>>(q_b, k_b, v_b, ctxh);

    // Phase 3: O-expert GEMM
    k_cast_wo<<<dim3(16, 64), 256, 0, stream>>>(Wo, WoT);
    k_gemm_o<<<dim3(64, 8), 256, 0, stream>>>(ctxh, WoT, go_d, out);
}

// Round 7
// 882.776 us; speedup vs baseline: 8.1078x; 1.2291x over previous
//
#include <hip/hip_runtime.h>
#include <math.h>

typedef unsigned short u16;
typedef unsigned int u32;
typedef __attribute__((ext_vector_type(8))) short short8;  // 8 bf16 (4 VGPRs)
typedef __attribute__((ext_vector_type(4))) float f32x4;   // MFMA C/D

// Problem constants
constexpr int cB = 4, cS = 2048, cD = 1024, cH = 8, cE = 8, cK = 2, cDH = 128;
constexpr int cBS = cB * cS;          // 8192
constexpr int cHE = cH * cE;          // 64

__device__ inline u16 f2bf(float f) {
    u32 u = __float_as_uint(f);
    u += 0x7fffu + ((u >> 16) & 1u);   // RNE
    return (u16)(u >> 16);
}
__device__ inline float bf2f(u16 h) { return __uint_as_float(((u32)h) << 16); }

// ---------------------------------------------------------------------------
// K1: gates — f32 (MUST stay f32: top-2 is discrete; bf16 logits flip
// near-tie selections vs the reference -> O(1) output error, see R5).
// ---------------------------------------------------------------------------
__global__ __launch_bounds__(256) void k_gates(
    const float* __restrict__ x, const float* __restrict__ sel_v,
    const float* __restrict__ sel_o,
    float* __restrict__ gv_d, float* __restrict__ go_d)
{
    __shared__ float xs[8][cD];       // 32 KB
    __shared__ float gs[8][2 * cHE];  // 4 KB
    const int row0 = blockIdx.x * 8;
    const int t = threadIdx.x;

    const float4* xv = (const float4*)(x + (size_t)row0 * cD);
    float4* xsv = (float4*)&xs[0][0];
    for (int i = t; i < 8 * cD / 4; i += 256) xsv[i] = xv[i];
    __syncthreads();

    const int wave = t >> 6, lane = t & 63;
    for (int p = wave; p < 2 * cHE; p += 4) {
        const float* srow = (p < cHE) ? (sel_v + (size_t)p * cD)
                                      : (sel_o + (size_t)(p - cHE) * cD);
        float acc[8] = {0, 0, 0, 0, 0, 0, 0, 0};
        for (int d = lane; d < cD; d += 64) {
            float w = srow[d];
#pragma unroll
            for (int r = 0; r < 8; r++) acc[r] += w * xs[r][d];
        }
#pragma unroll
        for (int off = 32; off > 0; off >>= 1) {
#pragma unroll
            for (int r = 0; r < 8; r++) acc[r] += __shfl_down(acc[r], off);
        }
        if (lane == 0) {
            for (int r = 0; r < 8; r++) gs[r][p] = acc[r];
        }
    }
    __syncthreads();

    if (t < 128) {
        const int r = t >> 4, h = (t >> 1) & 7, which = t & 1;
        const float* g = &gs[r][which * cHE + h * cE];
        int i0 = 0; float b0 = g[0];
        for (int e = 1; e < cE; e++) { if (g[e] > b0) { b0 = g[e]; i0 = e; } }
        int i1 = -1; float b1 = -3.0e38f;
        for (int e = 0; e < cE; e++) { if (e != i0 && g[e] > b1) { b1 = g[e]; i1 = e; } }
        const float w0 = 1.0f / (1.0f + expf(-b0));
        const float w1 = 1.0f / (1.0f + expf(-b1));
        float* dst = (which ? go_d : gv_d) + (size_t)(row0 + r) * 64 + h * 8;
#pragma unroll
        for (int e = 0; e < cE; e++)
            dst[e] = (e == i0) ? w0 : ((e == i1) ? w1 : 0.0f);
    }
}

// ---------------------------------------------------------------------------
// Elementwise f32 -> bf16 cast. grid = nfloat4/256 blocks x 256.
// ---------------------------------------------------------------------------
__global__ __launch_bounds__(256) void k_cast_f2b(
    const float* __restrict__ src, u16* __restrict__ dst)
{
    const size_t i = (size_t)blockIdx.x * 256 + threadIdx.x;  // float4 index
    float4 v = ((const float4*)src)[i];
    u32 lo = (u32)f2bf(v.x) | ((u32)f2bf(v.y) << 16);
    u32 hi = (u32)f2bf(v.z) | ((u32)f2bf(v.w) << 16);
    uint2 o; o.x = lo; o.y = hi;
    ((uint2*)dst)[i] = o;
}

// ---------------------------------------------------------------------------
// Transpose-cast Wv [HE][D][DH] f32 -> WvT [(he*128+dh)][d] bf16.
// ---------------------------------------------------------------------------
__global__ __launch_bounds__(256) void k_cast_wv(
    const float* __restrict__ Wv, u16* __restrict__ WvT)
{
    __shared__ float ld[64][132];  // [d-local][dh]
    const int d0 = blockIdx.x * 64, he = blockIdx.y;
    const int t = threadIdx.x;
    for (int p = 0; p < 8; p++) {
        const int slot = p * 256 + t, r = slot >> 5, c4 = slot & 31;
        float4 v = *(const float4*)(Wv + ((size_t)he * cD + d0 + r) * cDH + c4 * 4);
        ld[r][c4 * 4 + 0] = v.x; ld[r][c4 * 4 + 1] = v.y;
        ld[r][c4 * 4 + 2] = v.z; ld[r][c4 * 4 + 3] = v.w;
    }
    __syncthreads();
    for (int p = 0; p < 16; p++) {
        const int slot = p * 256 + t, dh = slot >> 5, c2 = slot & 31;
        u32 val = (u32)f2bf(ld[c2 * 2 + 0][dh]) | ((u32)f2bf(ld[c2 * 2 + 1][dh]) << 16);
        *(u32*)(WvT + (size_t)(he * cDH + dh) * cD + d0 + c2 * 2) = val;
    }
}

// ---------------------------------------------------------------------------
// Transpose-cast Wo [HE][DH][D] f32 -> WoT [m][(he*128+dh)] bf16.
// ---------------------------------------------------------------------------
__global__ __launch_bounds__(256) void k_cast_wo(
    const float* __restrict__ Wo, u16* __restrict__ WoT)
{
    __shared__ float ld[128][68];  // [dh][m-local]
    const int m0 = blockIdx.x * 64, he = blockIdx.y;
    const int t = threadIdx.x;
    for (int p = 0; p < 8; p++) {
        const int slot = p * 256 + t, r = slot >> 4, c4 = slot & 15;
        float4 v = *(const float4*)(Wo + ((size_t)he * cDH + r) * cD + m0 + c4 * 4);
        ld[r][c4 * 4 + 0] = v.x; ld[r][c4 * 4 + 1] = v.y;
        ld[r][c4 * 4 + 2] = v.z; ld[r][c4 * 4 + 3] = v.w;
    }
    __syncthreads();
    for (int p = 0; p < 16; p++) {
        const int slot = p * 256 + t, mr = slot >> 6, c2 = slot & 63;
        u32 val = (u32)f2bf(ld[c2 * 2 + 0][mr]) | ((u32)f2bf(ld[c2 * 2 + 1][mr]) << 16);
        *(u32*)(WoT + (size_t)(m0 + mr) * 8192 + he * cDH + c2 * 2) = val;
    }
}

// ---------------------------------------------------------------------------
// K-GEMM-V: v_b[b,h,s,:] = sum_e gv[bs,h,e]*(x[bs,:] @ Wv[h,e])  (bf16 out)
// Expert-outer: ungated staging; gate folded on f32 accumulator per expert.
// ---------------------------------------------------------------------------
__global__ __launch_bounds__(256, 2) void k_gemm_v(
    const u16* __restrict__ xh, const u16* __restrict__ WvT,
    const float* __restrict__ gv_d, u16* __restrict__ v_b)
{
    __shared__ u16 As[128 * 72];
    __shared__ u16 Bs[128 * 72];
    __shared__ float Gs[128][9];   // [row][e], +1 pad
    const int rt = blockIdx.x, h = blockIdx.y;
    const int r0 = rt * 128;
    const int t = threadIdx.x;
    const int w = t >> 6, lane = t & 63;
    const int wm = w >> 1, wn = w & 1;
    const int quad = lane >> 4, lm = lane & 15;

    {   // preload gates for this (block, h): 128 rows x 8 e
        const int row = t >> 1, half = t & 1;
        float4 g4 = *(const float4*)(gv_d + (size_t)(r0 + row) * 64 + h * 8 + half * 4);
        Gs[row][half * 4 + 0] = g4.x; Gs[row][half * 4 + 1] = g4.y;
        Gs[row][half * 4 + 2] = g4.z; Gs[row][half * 4 + 3] = g4.w;
    }

    f32x4 acc[4][4];
#pragma unroll
    for (int i = 0; i < 4; i++)
#pragma unroll
        for (int j = 0; j < 4; j++)
#pragma unroll
            for (int r = 0; r < 4; r++) acc[i][j][r] = 0.0f;

    for (int e = 0; e < cE; e++) {
        f32x4 acce[4][4];
#pragma unroll
        for (int i = 0; i < 4; i++)
#pragma unroll
            for (int j = 0; j < 4; j++)
#pragma unroll
                for (int r = 0; r < 4; r++) acce[i][j][r] = 0.0f;

        for (int kc = 0; kc < cD; kc += 64) {
#pragma unroll
            for (int p = 0; p < 4; p++) {
                const int slot = p * 256 + t, row = slot >> 3, seg = slot & 7;
                *(uint4*)(As + row * 72 + seg * 8) =
                    *(const uint4*)(xh + (size_t)(r0 + row) * cD + kc + seg * 8);
                *(uint4*)(Bs + row * 72 + seg * 8) =
                    *(const uint4*)(WvT + (size_t)((h * 8 + e) * cDH + row) * cD + kc + seg * 8);
            }
            __syncthreads();
#pragma unroll
            for (int ks = 0; ks < 64; ks += 32) {
                short8 av[4], bv[4];
#pragma unroll
                for (int i = 0; i < 4; i++)
                    av[i] = *(const short8*)(As + (wm * 64 + i * 16 + lm) * 72 + ks + quad * 8);
#pragma unroll
                for (int j = 0; j < 4; j++)
                    bv[j] = *(const short8*)(Bs + (wn * 64 + j * 16 + lm) * 72 + ks + quad * 8);
#pragma unroll
                for (int i = 0; i < 4; i++)
#pragma unroll
                    for (int j = 0; j < 4; j++)
                        acce[i][j] = __builtin_amdgcn_mfma_f32_16x16x32_bf16(av[i], bv[j], acce[i][j], 0, 0, 0);
            }
            __syncthreads();
        }
        // fold gate: acc += g[row][e] * acce
#pragma unroll
        for (int i = 0; i < 4; i++)
#pragma unroll
            for (int r = 0; r < 4; r++) {
                const float g = Gs[wm * 64 + i * 16 + quad * 4 + r][e];
#pragma unroll
                for (int j = 0; j < 4; j++) acc[i][j][r] += g * acce[i][j][r];
            }
    }
#pragma unroll
    for (int i = 0; i < 4; i++)
#pragma unroll
        for (int r = 0; r < 4; r++) {
            const int row = r0 + wm * 64 + i * 16 + quad * 4 + r;
            const int b = row >> 11, s = row & (cS - 1);
            u16* dst = v_b + ((size_t)(b * cH + h) * cS + s) * cDH;
#pragma unroll
            for (int j = 0; j < 4; j++)
                dst[wn * 64 + j * 16 + lm] = f2bf(acc[i][j][r]);
        }
}

// ---------------------------------------------------------------------------
// K-GEMM-O: out[bs,:] = sum_{h,e} go[bs,h,e]*(ctx[bs,h,:] @ Wo[h,e])
// he-outer: ungated staging; gate folded on f32 accumulator per he chunk.
// ---------------------------------------------------------------------------
__global__ __launch_bounds__(256, 2) void k_gemm_o(
    const u16* __restrict__ ctxh, const u16* __restrict__ WoT,
    const float* __restrict__ go_d, float* __restrict__ out)
{
    __shared__ u16 As[128 * 72];
    __shared__ u16 Bs[128 * 72];
    __shared__ float Gs[128][65];  // [row][he], +1 pad (33 KB)
    const int rt = blockIdx.x, nt = blockIdx.y;
    const int r0 = rt * 128;
    const int t = threadIdx.x;
    const int w = t >> 6, lane = t & 63;
    const int wm = w >> 1, wn = w & 1;
    const int quad = lane >> 4, lm = lane & 15;

#pragma unroll
    for (int p = 0; p < 8; p++) {  // 2048 float4 = 128 rows x 16
        const int slot = p * 256 + t, row = slot >> 4, seg = slot & 15;
        float4 g4 = *(const float4*)(go_d + (size_t)(r0 + row) * 64 + seg * 4);
        Gs[row][seg * 4 + 0] = g4.x; Gs[row][seg * 4 + 1] = g4.y;
        Gs[row][seg * 4 + 2] = g4.z; Gs[row][seg * 4 + 3] = g4.w;
    }

    f32x4 acc[4][4];
#pragma unroll
    for (int i = 0; i < 4; i++)
#pragma unroll
        for (int j = 0; j < 4; j++)
#pragma unroll
            for (int r = 0; r < 4; r++) acc[i][j][r] = 0.0f;

    for (int he = 0; he < cHE; he++) {
        f32x4 acce[4][4];
#pragma unroll
        for (int i = 0; i < 4; i++)
#pragma unroll
            for (int j = 0; j < 4; j++)
#pragma unroll
                for (int r = 0; r < 4; r++) acce[i][j][r] = 0.0f;

#pragma unroll
        for (int kc = 0; kc < 2; kc++) {
            const int ccol = (he >> 3) * 128 + kc * 64;  // physical ctx column
#pragma unroll
            for (int p = 0; p < 4; p++) {
                const int slot = p * 256 + t, row = slot >> 3, seg = slot & 7;
                *(uint4*)(As + row * 72 + seg * 8) =
                    *(const uint4*)(ctxh + (size_t)(r0 + row) * cD + ccol + seg * 8);
                *(uint4*)(Bs + row * 72 + seg * 8) =
                    *(const uint4*)(WoT + (size_t)(nt * 128 + row) * 8192 + he * 128 + kc * 64 + seg * 8);
            }
            __syncthreads();
#pragma unroll
            for (int ks = 0; ks < 64; ks += 32) {
                short8 av[4], bv[4];
#pragma unroll
                for (int i = 0; i < 4; i++)
                    av[i] = *(const short8*)(As + (wm * 64 + i * 16 + lm) * 72 + ks + quad * 8);
#pragma unroll
                for (int j = 0; j < 4; j++)
                    bv[j] = *(const short8*)(Bs + (wn * 64 + j * 16 + lm) * 72 + ks + quad * 8);
#pragma unroll
                for (int i = 0; i < 4; i++)
#pragma unroll
                    for (int j = 0; j < 4; j++)
                        acce[i][j] = __builtin_amdgcn_mfma_f32_16x16x32_bf16(av[i], bv[j], acce[i][j], 0, 0, 0);
            }
            __syncthreads();
        }
#pragma unroll
        for (int i = 0; i < 4; i++)
#pragma unroll
            for (int r = 0; r < 4; r++) {
                const float g = Gs[wm * 64 + i * 16 + quad * 4 + r][he];
#pragma unroll
                for (int j = 0; j < 4; j++) acc[i][j][r] += g * acce[i][j][r];
            }
    }
#pragma unroll
    for (int i = 0; i < 4; i++)
#pragma unroll
        for (int r = 0; r < 4; r++) {
            const int row = r0 + wm * 64 + i * 16 + quad * 4 + r;
            float* dst = out + (size_t)row * cD + nt * 128;
#pragma unroll
            for (int j = 0; j < 4; j++)
                dst[wn * 64 + j * 16 + lm] = acc[i][j][r];
        }
}

// ---------------------------------------------------------------------------
// K-QKPROJ (MFMA): q/k = x @ Wq^T / Wk^T per head. f32 out [b,h,s,dh].
// ---------------------------------------------------------------------------
__global__ __launch_bounds__(256, 2) void k_qkproj_mfma(
    const u16* __restrict__ xh, const u16* __restrict__ Wqb,
    const u16* __restrict__ Wkb, float* __restrict__ q_t, float* __restrict__ k_t)
{
    __shared__ u16 As[128 * 72];
    __shared__ u16 Bs[128 * 72];
    const int rt = blockIdx.x, nt = blockIdx.y;
    const bool isK = nt >= cH;
    const int h = isK ? nt - cH : nt;
    const u16* Wb = isK ? Wkb : Wqb;
    float* outp = isK ? k_t : q_t;
    const int r0 = rt * 128;
    const int t = threadIdx.x;
    const int w = t >> 6, lane = t & 63;
    const int wm = w >> 1, wn = w & 1;
    const int quad = lane >> 4, lm = lane & 15;

    f32x4 acc[4][4];
#pragma unroll
    for (int i = 0; i < 4; i++)
#pragma unroll
        for (int j = 0; j < 4; j++)
#pragma unroll
            for (int r = 0; r < 4; r++) acc[i][j][r] = 0.0f;

    for (int kc = 0; kc < cD; kc += 64) {
#pragma unroll
        for (int p = 0; p < 4; p++) {
            const int slot = p * 256 + t, row = slot >> 3, seg = slot & 7;
            *(uint4*)(As + row * 72 + seg * 8) =
                *(const uint4*)(xh + (size_t)(r0 + row) * cD + kc + seg * 8);
            *(uint4*)(Bs + row * 72 + seg * 8) =
                *(const uint4*)(Wb + (size_t)(h * cDH + row) * cD + kc + seg * 8);
        }
        __syncthreads();
#pragma unroll
        for (int ks = 0; ks < 64; ks += 32) {
            short8 av[4], bv[4];
#pragma unroll
            for (int i = 0; i < 4; i++)
                av[i] = *(const short8*)(As + (wm * 64 + i * 16 + lm) * 72 + ks + quad * 8);
#pragma unroll
            for (int j = 0; j < 4; j++)
                bv[j] = *(const short8*)(Bs + (wn * 64 + j * 16 + lm) * 72 + ks + quad * 8);
#pragma unroll
            for (int i = 0; i < 4; i++)
#pragma unroll
                for (int j = 0; j < 4; j++)
                    acc[i][j] = __builtin_amdgcn_mfma_f32_16x16x32_bf16(av[i], bv[j], acc[i][j], 0, 0, 0);
        }
        __syncthreads();
    }
#pragma unroll
    for (int i = 0; i < 4; i++)
#pragma unroll
        for (int r = 0; r < 4; r++) {
            const int row = r0 + wm * 64 + i * 16 + quad * 4 + r;
            const int b = row >> 11, s = row & (cS - 1);
            float* dst = outp + ((size_t)(b * cH + h) * cS + s) * cDH;
#pragma unroll
            for (int j = 0; j < 4; j++)
                dst[wn * 64 + j * 16 + lm] = acc[i][j][r];
        }
}

// ---------------------------------------------------------------------------
// RoPE + cast: read f32 q_t/k_t [b,h,s,dh], write bf16 q_b/k_b same layout.
// ---------------------------------------------------------------------------
__global__ __launch_bounds__(256) void k_rope_cast(
    const float* __restrict__ q_t, const float* __restrict__ k_t,
    const int* __restrict__ positions,
    u16* __restrict__ q_b, u16* __restrict__ k_b)
{
    const int total = cB * cH * cS * (cDH / 2);
    const int idx = blockIdx.x * 256 + threadIdx.x;
    const int which = (idx >= total) ? 1 : 0;
    const int id = which ? idx - total : idx;
    const int i = id & 63;
    const int bhs = id >> 6;
    const int s = bhs & (cS - 1);
    const int b = (bhs >> 11) >> 3;
    const float* src = (which ? k_t : q_t) + (size_t)bhs * cDH;
    u16* dst = (which ? k_b : q_b) + (size_t)bhs * cDH;
    const int pos = positions[b * cS + s];
    const float freq = powf(10000.0f, -(float)i / 64.0f);
    const float ang = (float)pos * freq;
    const float c = cosf(ang), sn = sinf(ang);
    const float t1 = src[i], t2 = src[i + 64];
    dst[i] = f2bf(t1 * c - t2 * sn);
    dst[i + 64] = f2bf(t2 * c + t1 * sn);
}

// ---------------------------------------------------------------------------
// K5: MFMA flash attention. BQ=128 (4 waves x 32 rows), BK=64, DH=128.
// Each K/V B-fragment feeds 2 MFMAs (halved LDS reads per MFMA).
// grid (16 q-tiles zigzagged, 8 h, 4 b); 2 blocks/CU (54 KB LDS).
// ---------------------------------------------------------------------------
__global__ __launch_bounds__(256, 2) void k_attn_mfma(
    const u16* __restrict__ qb, const u16* __restrict__ kb,
    const u16* __restrict__ vb, u16* __restrict__ ctxh)
{
    __shared__ u16 Ks[64][136];    // [kv][dh], 17.4 KB
    __shared__ u16 VsT[128][72];   // [dh][kv], 18.4 KB
    __shared__ u16 Ps[4][32][72];  // per-wave P strip [qrow][kv], 18.4 KB

    const int combined = blockIdx.z * 8 + blockIdx.y;  // b*8+h, 0..31
    const int qtv = (combined < 16) ? (15 - (int)blockIdx.x) : (int)blockIdx.x;
    const int h = blockIdx.y, b = blockIdx.z;
    const int q0 = qtv * 128;
    const int t = threadIdx.x;
    const int w = t >> 6, lane = t & 63;
    const int quad = lane >> 4, lm = lane & 15;
    const size_t bh = (size_t)(b * cH + h) * cS;
    const u16* kbase = kb + bh * cDH;
    const u16* vbase = vb + bh * cDH;

    // Q fragments: wave w owns rows q0+w*32 .. +31 (two 16-row m-subtiles)
    short8 aq[2][4];
#pragma unroll
    for (int mi = 0; mi < 2; mi++) {
        const u16* qrow = qb + (bh + q0 + w * 32 + mi * 16 + lm) * cDH;
#pragma unroll
        for (int ks = 0; ks < 4; ks++)
            aq[mi][ks] = *(const short8*)(qrow + ks * 32 + quad * 8);
    }

    f32x4 o_acc[2][8];
#pragma unroll
    for (int mi = 0; mi < 2; mi++)
#pragma unroll
        for (int j = 0; j < 8; j++)
#pragma unroll
            for (int r = 0; r < 4; r++) o_acc[mi][j][r] = 0.0f;
    float m_r[2][4], l_r[2][4];
#pragma unroll
    for (int mi = 0; mi < 2; mi++)
#pragma unroll
        for (int r = 0; r < 4; r++) { m_r[mi][r] = -1.0e30f; l_r[mi][r] = 0.0f; }
    const float scale = 0.08838834764831845f;  // 1/sqrt(128)
    const int nkt = 2 * qtv + 2;

    for (int kt = 0; kt < nkt; kt++) {
        const int k0 = kt * 64;
        // stage K: 64 rows x 128 dh
#pragma unroll
        for (int p = 0; p < 4; p++) {
            const int slot = p * 256 + t, row = slot >> 4, seg = slot & 15;
            *(uint4*)&Ks[row][seg * 8] =
                *(const uint4*)(kbase + (size_t)(k0 + row) * cDH + seg * 8);
        }
        // stage V transposed
        {
            const int rq = t & 15, seg = t >> 4;
            uint4 r0v = *(const uint4*)(vbase + (size_t)(k0 + rq * 4 + 0) * cDH + seg * 8);
            uint4 r1v = *(const uint4*)(vbase + (size_t)(k0 + rq * 4 + 1) * cDH + seg * 8);
            uint4 r2v = *(const uint4*)(vbase + (size_t)(k0 + rq * 4 + 2) * cDH + seg * 8);
            uint4 r3v = *(const uint4*)(vbase + (size_t)(k0 + rq * 4 + 3) * cDH + seg * 8);
            const u16* p0 = (const u16*)&r0v; const u16* p1 = (const u16*)&r1v;
            const u16* p2 = (const u16*)&r2v; const u16* p3 = (const u16*)&r3v;
#pragma unroll
            for (int jj = 0; jj < 8; jj++) {
                ushort4 val;
                val.x = p0[jj]; val.y = p1[jj]; val.z = p2[jj]; val.w = p3[jj];
                *(ushort4*)&VsT[seg * 8 + jj][rq * 4] = val;
            }
        }
        __syncthreads();

        // QK^T: 32 rows x 64 cols, shared B-fragments across the 2 m-subtiles
        f32x4 s[2][4];
#pragma unroll
        for (int mi = 0; mi < 2; mi++)
#pragma unroll
            for (int j = 0; j < 4; j++)
#pragma unroll
                for (int r = 0; r < 4; r++) s[mi][j][r] = 0.0f;
#pragma unroll
        for (int ks = 0; ks < 4; ks++) {
#pragma unroll
            for (int j = 0; j < 4; j++) {
                short8 bv = *(const short8*)&Ks[j * 16 + lm][ks * 32 + quad * 8];
                s[0][j] = __builtin_amdgcn_mfma_f32_16x16x32_bf16(aq[0][ks], bv, s[0][j], 0, 0, 0);
                s[1][j] = __builtin_amdgcn_mfma_f32_16x16x32_bf16(aq[1][ks], bv, s[1][j], 0, 0, 0);
            }
        }
        // scale + causal mask (mask needed only for the last two k-tiles)
        if (kt >= nkt - 2) {
#pragma unroll
            for (int mi = 0; mi < 2; mi++)
#pragma unroll
                for (int j = 0; j < 4; j++) {
                    const int colg = k0 + j * 16 + lm;
#pragma unroll
                    for (int r = 0; r < 4; r++) {
                        const int rowg = q0 + w * 32 + mi * 16 + quad * 4 + r;
                        s[mi][j][r] = (colg <= rowg) ? s[mi][j][r] * scale : -1.0e30f;
                    }
                }
        } else {
#pragma unroll
            for (int mi = 0; mi < 2; mi++)
#pragma unroll
                for (int j = 0; j < 4; j++)
#pragma unroll
                    for (int r = 0; r < 4; r++) s[mi][j][r] *= scale;
        }
        // online softmax per m-subtile (row stats across the quad's 16 lanes)
#pragma unroll
        for (int mi = 0; mi < 2; mi++) {
            float mt[4];
#pragma unroll
            for (int r = 0; r < 4; r++)
                mt[r] = fmaxf(fmaxf(s[mi][0][r], s[mi][1][r]), fmaxf(s[mi][2][r], s[mi][3][r]));
#pragma unroll
            for (int off = 1; off < 16; off <<= 1)
#pragma unroll
                for (int r = 0; r < 4; r++) mt[r] = fmaxf(mt[r], __shfl_xor(mt[r], off));
            float alpha[4], rs[4];
#pragma unroll
            for (int r = 0; r < 4; r++) {
                const float mn = fmaxf(m_r[mi][r], mt[r]);
                alpha[r] = __expf(m_r[mi][r] - mn);
                m_r[mi][r] = mn;
                rs[r] = 0.0f;
            }
#pragma unroll
            for (int j = 0; j < 4; j++)
#pragma unroll
                for (int r = 0; r < 4; r++) {
                    const float p = __expf(s[mi][j][r] - m_r[mi][r]);
                    s[mi][j][r] = p;
                    rs[r] += p;
                }
#pragma unroll
            for (int off = 1; off < 16; off <<= 1)
#pragma unroll
                for (int r = 0; r < 4; r++) rs[r] += __shfl_xor(rs[r], off);
#pragma unroll
            for (int r = 0; r < 4; r++) l_r[mi][r] = l_r[mi][r] * alpha[r] + rs[r];
#pragma unroll
            for (int j = 0; j < 8; j++)
#pragma unroll
                for (int r = 0; r < 4; r++) o_acc[mi][j][r] *= alpha[r];
            // P -> wave-private LDS strip
#pragma unroll
            for (int j = 0; j < 4; j++)
#pragma unroll
                for (int r = 0; r < 4; r++)
                    Ps[w][mi * 16 + quad * 4 + r][j * 16 + lm] = f2bf(s[mi][j][r]);
        }
        // PV: O[32 x 128] += P[32 x 64] * V[64 x 128], shared B-fragments
#pragma unroll
        for (int ks2 = 0; ks2 < 2; ks2++) {
            short8 ap0 = *(const short8*)&Ps[w][lm][ks2 * 32 + quad * 8];
            short8 ap1 = *(const short8*)&Ps[w][16 + lm][ks2 * 32 + quad * 8];
#pragma unroll
            for (int j2 = 0; j2 < 8; j2++) {
                short8 bv = *(const short8*)&VsT[j2 * 16 + lm][ks2 * 32 + quad * 8];
                o_acc[0][j2] = __builtin_amdgcn_mfma_f32_16x16x32_bf16(ap0, bv, o_acc[0][j2], 0, 0, 0);
                o_acc[1][j2] = __builtin_amdgcn_mfma_f32_16x16x32_bf16(ap1, bv, o_acc[1][j2], 0, 0, 0);
            }
        }
        __syncthreads();
    }
    // epilogue: ctxh [b,s,h,dh] bf16
#pragma unroll
    for (int mi = 0; mi < 2; mi++)
#pragma unroll
        for (int r = 0; r < 4; r++) {
            const float inv = 1.0f / l_r[mi][r];
            const int sg = q0 + w * 32 + mi * 16 + quad * 4 + r;
            u16* dst = ctxh + (((size_t)b * cS + sg) * cH + h) * cDH;
#pragma unroll
            for (int j2 = 0; j2 < 8; j2++)
                dst[j2 * 16 + lm] = f2bf(o_acc[mi][j2][r] * inv);
        }
}

// ---------------------------------------------------------------------------
extern "C" void kernel_launch(void* const* d_in, const int* in_sizes, int n_in,
                              void* d_out, int out_size, void* d_ws, size_t ws_size,
                              hipStream_t stream)
{
    const float* x = (const float*)d_in[0];
    const float* Wq = (const float*)d_in[1];
    const float* Wk = (const float*)d_in[2];
    const float* Wv = (const float*)d_in[3];
    const float* Wo = (const float*)d_in[4];
    const float* sel_v = (const float*)d_in[5];
    const float* sel_o = (const float*)d_in[6];
    const int* positions = (const int*)d_in[7];
    float* out = (float*)d_out;

    char* ws = (char*)d_ws;
    size_t off = 0;
    auto alloc = [&](size_t bytes) -> void* {
        void* p = ws + off;
        off += (bytes + 255) & ~(size_t)255;
        return p;
    };
    const size_t big = (size_t)cB * cH * cS * cDH * sizeof(float);  // 32 MB
    const size_t half = big / 2;                                    // 16 MB
    // Overlays (stream-ordered lifetimes):
    //   R1: WvT bf16 (ph1) -> q_t f32 (ph2)
    //   R2: k_t f32 (ph2) -> WoT bf16 (ph3)
    //   R3: [0,16M) v_b bf16; [16M,32M) Wqb+Wkb bf16 -> ctxh bf16
    //   R4: [0,16M) xh bf16 -> q_b bf16; [16M,32M) k_b bf16
    char* R1 = (char*)alloc(big);
    char* R2 = (char*)alloc(big);
    char* R3 = (char*)alloc(big);
    char* R4 = (char*)alloc(big);
    float* gv_d = (float*)alloc((size_t)cBS * 64 * sizeof(float));  // 2 MB
    float* go_d = (float*)alloc((size_t)cBS * 64 * sizeof(float));  // 2 MB

    u16* WvT = (u16*)R1;
    float* q_t = (float*)R1;
    float* k_t = (float*)R2;
    u16* WoT = (u16*)R2;
    u16* v_b = (u16*)R3;
    u16* Wqb = (u16*)(R3 + half);
    u16* Wkb = (u16*)(R3 + half + ((size_t)cD * cD * 2));
    u16* ctxh = (u16*)(R3 + half);
    u16* xh = (u16*)R4;
    u16* q_b = (u16*)R4;
    u16* k_b = (u16*)(R4 + half);

    // Phase 1: gates (f32), casts, V-expert GEMM
    k_gates<<<cBS / 8, 256, 0, stream>>>(x, sel_v, sel_o, gv_d, go_d);
    k_cast_f2b<<<8192, 256, 0, stream>>>(x, xh);
    k_cast_wv<<<dim3(16, 64), 256, 0, stream>>>(Wv, WvT);
    k_gemm_v<<<dim3(64, 8), 256, 0, stream>>>(xh, WvT, gv_d, v_b);

    // Phase 2: Q/K projection (MFMA) + RoPE-cast + MFMA attention
    k_cast_f2b<<<1024, 256, 0, stream>>>(Wq, Wqb);
    k_cast_f2b<<<1024, 256, 0, stream>>>(Wk, Wkb);
    k_qkproj_mfma<<<dim3(64, 16), 256, 0, stream>>>(xh, Wqb, Wkb, q_t, k_t);
    k_rope_cast<<<(2 * cB * cH * cS * (cDH / 2)) / 256, 256, 0, stream>>>(
        q_t, k_t, positions, q_b, k_b);
    k_attn_mfma<<<dim3(16, 8, 4), 256, 0, stream>>>(q_b, k_b, v_b, ctxh);

    // Phase 3: O-expert GEMM
    k_cast_wo<<<dim3(16, 64), 256, 0, stream>>>(Wo, WoT);
    k_gemm_o<<<dim3(64, 8), 256, 0, stream>>>(ctxh, WoT, go_d, out);
}

// Round 8
// 873.377 us; speedup vs baseline: 8.1951x; 1.0108x over previous
//
#include <hip/hip_runtime.h>
#include <math.h>

typedef unsigned short u16;
typedef unsigned int u32;
typedef __attribute__((ext_vector_type(8))) short short8;  // 8 bf16 (4 VGPRs)
typedef __attribute__((ext_vector_type(4))) float f32x4;   // MFMA C/D

// Problem constants
constexpr int cB = 4, cS = 2048, cD = 1024, cH = 8, cE = 8, cK = 2, cDH = 128;
constexpr int cBS = cB * cS;          // 8192
constexpr int cHE = cH * cE;          // 64

__device__ inline u16 f2bf(float f) {
    u32 u = __float_as_uint(f);
    u += 0x7fffu + ((u >> 16) & 1u);   // RNE
    return (u16)(u >> 16);
}
__device__ inline float bf2f(u16 h) { return __uint_as_float(((u32)h) << 16); }

// ---------------------------------------------------------------------------
// K1: gates — f32 (MUST stay f32: top-2 is discrete; bf16 logits flip
// near-tie selections vs the reference -> O(1) output error, see R5).
// R8: vectorized (float4 sel loads, b128 xs reads, 2 p in flight) to kill
// the latency serialization seen in R7 (221 us @ VALUBusy 19%).
// ---------------------------------------------------------------------------
__global__ __launch_bounds__(256) void k_gates(
    const float* __restrict__ x, const float* __restrict__ sel_v,
    const float* __restrict__ sel_o,
    float* __restrict__ gv_d, float* __restrict__ go_d)
{
    __shared__ float xs[8][cD];       // 32 KB
    __shared__ float gs[8][2 * cHE];  // 4 KB
    const int row0 = blockIdx.x * 8;
    const int t = threadIdx.x;

    const float4* xv = (const float4*)(x + (size_t)row0 * cD);
    float4* xsv = (float4*)&xs[0][0];
    for (int i = t; i < 8 * cD / 4; i += 256) xsv[i] = xv[i];
    __syncthreads();

    const int wave = t >> 6, lane = t & 63;
    // wave w owns p = w*32 .. w*32+31, processed as 16 pairs
    for (int pp = 0; pp < 16; pp++) {
        const int p0 = wave * 32 + pp * 2;
        const int p1 = p0 + 1;
        const float* s0 = (p0 < cHE) ? (sel_v + (size_t)p0 * cD)
                                     : (sel_o + (size_t)(p0 - cHE) * cD);
        const float* s1 = (p1 < cHE) ? (sel_v + (size_t)p1 * cD)
                                     : (sel_o + (size_t)(p1 - cHE) * cD);
        float acc0[8] = {0, 0, 0, 0, 0, 0, 0, 0};
        float acc1[8] = {0, 0, 0, 0, 0, 0, 0, 0};
#pragma unroll
        for (int dg = 0; dg < 4; dg++) {
            const int d0 = dg * 256 + lane * 4;
            const float4 w0 = *(const float4*)(s0 + d0);
            const float4 w1 = *(const float4*)(s1 + d0);
#pragma unroll
            for (int r = 0; r < 8; r++) {
                const float4 xr = *(const float4*)&xs[r][d0];
                acc0[r] += w0.x * xr.x + w0.y * xr.y + w0.z * xr.z + w0.w * xr.w;
                acc1[r] += w1.x * xr.x + w1.y * xr.y + w1.z * xr.z + w1.w * xr.w;
            }
        }
#pragma unroll
        for (int off = 32; off > 0; off >>= 1) {
#pragma unroll
            for (int r = 0; r < 8; r++) {
                acc0[r] += __shfl_down(acc0[r], off);
                acc1[r] += __shfl_down(acc1[r], off);
            }
        }
        if (lane == 0) {
#pragma unroll
            for (int r = 0; r < 8; r++) {
                gs[r][p0] = acc0[r];
                gs[r][p1] = acc1[r];
            }
        }
    }
    __syncthreads();

    if (t < 128) {
        const int r = t >> 4, h = (t >> 1) & 7, which = t & 1;
        const float* g = &gs[r][which * cHE + h * cE];
        int i0 = 0; float b0 = g[0];
        for (int e = 1; e < cE; e++) { if (g[e] > b0) { b0 = g[e]; i0 = e; } }
        int i1 = -1; float b1 = -3.0e38f;
        for (int e = 0; e < cE; e++) { if (e != i0 && g[e] > b1) { b1 = g[e]; i1 = e; } }
        const float w0 = 1.0f / (1.0f + expf(-b0));
        const float w1 = 1.0f / (1.0f + expf(-b1));
        float* dst = (which ? go_d : gv_d) + (size_t)(row0 + r) * 64 + h * 8;
#pragma unroll
        for (int e = 0; e < cE; e++)
            dst[e] = (e == i0) ? w0 : ((e == i1) ? w1 : 0.0f);
    }
}

// ---------------------------------------------------------------------------
// Elementwise f32 -> bf16 cast. grid = nfloat4/256 blocks x 256.
// ---------------------------------------------------------------------------
__global__ __launch_bounds__(256) void k_cast_f2b(
    const float* __restrict__ src, u16* __restrict__ dst)
{
    const size_t i = (size_t)blockIdx.x * 256 + threadIdx.x;  // float4 index
    float4 v = ((const float4*)src)[i];
    u32 lo = (u32)f2bf(v.x) | ((u32)f2bf(v.y) << 16);
    u32 hi = (u32)f2bf(v.z) | ((u32)f2bf(v.w) << 16);
    uint2 o; o.x = lo; o.y = hi;
    ((uint2*)dst)[i] = o;
}

// ---------------------------------------------------------------------------
// Transpose-cast Wv [HE][D][DH] f32 -> WvT [(he*128+dh)][d] bf16.
// ---------------------------------------------------------------------------
__global__ __launch_bounds__(256) void k_cast_wv(
    const float* __restrict__ Wv, u16* __restrict__ WvT)
{
    __shared__ float ld[64][132];  // [d-local][dh]
    const int d0 = blockIdx.x * 64, he = blockIdx.y;
    const int t = threadIdx.x;
    for (int p = 0; p < 8; p++) {
        const int slot = p * 256 + t, r = slot >> 5, c4 = slot & 31;
        float4 v = *(const float4*)(Wv + ((size_t)he * cD + d0 + r) * cDH + c4 * 4);
        ld[r][c4 * 4 + 0] = v.x; ld[r][c4 * 4 + 1] = v.y;
        ld[r][c4 * 4 + 2] = v.z; ld[r][c4 * 4 + 3] = v.w;
    }
    __syncthreads();
    for (int p = 0; p < 16; p++) {
        const int slot = p * 256 + t, dh = slot >> 5, c2 = slot & 31;
        u32 val = (u32)f2bf(ld[c2 * 2 + 0][dh]) | ((u32)f2bf(ld[c2 * 2 + 1][dh]) << 16);
        *(u32*)(WvT + (size_t)(he * cDH + dh) * cD + d0 + c2 * 2) = val;
    }
}

// ---------------------------------------------------------------------------
// Transpose-cast Wo [HE][DH][D] f32 -> WoT [m][(he*128+dh)] bf16.
// ---------------------------------------------------------------------------
__global__ __launch_bounds__(256) void k_cast_wo(
    const float* __restrict__ Wo, u16* __restrict__ WoT)
{
    __shared__ float ld[128][68];  // [dh][m-local]
    const int m0 = blockIdx.x * 64, he = blockIdx.y;
    const int t = threadIdx.x;
    for (int p = 0; p < 8; p++) {
        const int slot = p * 256 + t, r = slot >> 4, c4 = slot & 15;
        float4 v = *(const float4*)(Wo + ((size_t)he * cDH + r) * cD + m0 + c4 * 4);
        ld[r][c4 * 4 + 0] = v.x; ld[r][c4 * 4 + 1] = v.y;
        ld[r][c4 * 4 + 2] = v.z; ld[r][c4 * 4 + 3] = v.w;
    }
    __syncthreads();
    for (int p = 0; p < 16; p++) {
        const int slot = p * 256 + t, mr = slot >> 6, c2 = slot & 63;
        u32 val = (u32)f2bf(ld[c2 * 2 + 0][mr]) | ((u32)f2bf(ld[c2 * 2 + 1][mr]) << 16);
        *(u32*)(WoT + (size_t)(m0 + mr) * 8192 + he * cDH + c2 * 2) = val;
    }
}

// ---------------------------------------------------------------------------
// K-GEMM-V: v_b[b,h,s,:] = sum_e gv[bs,h,e]*(x[bs,:] @ Wv[h,e])  (bf16 out)
// Expert-outer: ungated staging; gate folded on f32 accumulator per expert.
// ---------------------------------------------------------------------------
__global__ __launch_bounds__(256, 2) void k_gemm_v(
    const u16* __restrict__ xh, const u16* __restrict__ WvT,
    const float* __restrict__ gv_d, u16* __restrict__ v_b)
{
    __shared__ u16 As[128 * 72];
    __shared__ u16 Bs[128 * 72];
    __shared__ float Gs[128][9];   // [row][e], +1 pad
    const int rt = blockIdx.x, h = blockIdx.y;
    const int r0 = rt * 128;
    const int t = threadIdx.x;
    const int w = t >> 6, lane = t & 63;
    const int wm = w >> 1, wn = w & 1;
    const int quad = lane >> 4, lm = lane & 15;

    {   // preload gates for this (block, h): 128 rows x 8 e
        const int row = t >> 1, half = t & 1;
        float4 g4 = *(const float4*)(gv_d + (size_t)(r0 + row) * 64 + h * 8 + half * 4);
        Gs[row][half * 4 + 0] = g4.x; Gs[row][half * 4 + 1] = g4.y;
        Gs[row][half * 4 + 2] = g4.z; Gs[row][half * 4 + 3] = g4.w;
    }

    f32x4 acc[4][4];
#pragma unroll
    for (int i = 0; i < 4; i++)
#pragma unroll
        for (int j = 0; j < 4; j++)
#pragma unroll
            for (int r = 0; r < 4; r++) acc[i][j][r] = 0.0f;

    for (int e = 0; e < cE; e++) {
        f32x4 acce[4][4];
#pragma unroll
        for (int i = 0; i < 4; i++)
#pragma unroll
            for (int j = 0; j < 4; j++)
#pragma unroll
                for (int r = 0; r < 4; r++) acce[i][j][r] = 0.0f;

        for (int kc = 0; kc < cD; kc += 64) {
#pragma unroll
            for (int p = 0; p < 4; p++) {
                const int slot = p * 256 + t, row = slot >> 3, seg = slot & 7;
                *(uint4*)(As + row * 72 + seg * 8) =
                    *(const uint4*)(xh + (size_t)(r0 + row) * cD + kc + seg * 8);
                *(uint4*)(Bs + row * 72 + seg * 8) =
                    *(const uint4*)(WvT + (size_t)((h * 8 + e) * cDH + row) * cD + kc + seg * 8);
            }
            __syncthreads();
#pragma unroll
            for (int ks = 0; ks < 64; ks += 32) {
                short8 av[4], bv[4];
#pragma unroll
                for (int i = 0; i < 4; i++)
                    av[i] = *(const short8*)(As + (wm * 64 + i * 16 + lm) * 72 + ks + quad * 8);
#pragma unroll
                for (int j = 0; j < 4; j++)
                    bv[j] = *(const short8*)(Bs + (wn * 64 + j * 16 + lm) * 72 + ks + quad * 8);
#pragma unroll
                for (int i = 0; i < 4; i++)
#pragma unroll
                    for (int j = 0; j < 4; j++)
                        acce[i][j] = __builtin_amdgcn_mfma_f32_16x16x32_bf16(av[i], bv[j], acce[i][j], 0, 0, 0);
            }
            __syncthreads();
        }
        // fold gate: acc += g[row][e] * acce
#pragma unroll
        for (int i = 0; i < 4; i++)
#pragma unroll
            for (int r = 0; r < 4; r++) {
                const float g = Gs[wm * 64 + i * 16 + quad * 4 + r][e];
#pragma unroll
                for (int j = 0; j < 4; j++) acc[i][j][r] += g * acce[i][j][r];
            }
    }
#pragma unroll
    for (int i = 0; i < 4; i++)
#pragma unroll
        for (int r = 0; r < 4; r++) {
            const int row = r0 + wm * 64 + i * 16 + quad * 4 + r;
            const int b = row >> 11, s = row & (cS - 1);
            u16* dst = v_b + ((size_t)(b * cH + h) * cS + s) * cDH;
#pragma unroll
            for (int j = 0; j < 4; j++)
                dst[wn * 64 + j * 16 + lm] = f2bf(acc[i][j][r]);
        }
}

// ---------------------------------------------------------------------------
// K-GEMM-O: out[bs,:] = sum_{h,e} go[bs,h,e]*(ctx[bs,h,:] @ Wo[h,e])
// he-outer: ungated staging; gate folded on f32 accumulator per he chunk.
// ---------------------------------------------------------------------------
__global__ __launch_bounds__(256, 2) void k_gemm_o(
    const u16* __restrict__ ctxh, const u16* __restrict__ WoT,
    const float* __restrict__ go_d, float* __restrict__ out)
{
    __shared__ u16 As[128 * 72];
    __shared__ u16 Bs[128 * 72];
    __shared__ float Gs[128][65];  // [row][he], +1 pad (33 KB)
    const int rt = blockIdx.x, nt = blockIdx.y;
    const int r0 = rt * 128;
    const int t = threadIdx.x;
    const int w = t >> 6, lane = t & 63;
    const int wm = w >> 1, wn = w & 1;
    const int quad = lane >> 4, lm = lane & 15;

#pragma unroll
    for (int p = 0; p < 8; p++) {  // 2048 float4 = 128 rows x 16
        const int slot = p * 256 + t, row = slot >> 4, seg = slot & 15;
        float4 g4 = *(const float4*)(go_d + (size_t)(r0 + row) * 64 + seg * 4);
        Gs[row][seg * 4 + 0] = g4.x; Gs[row][seg * 4 + 1] = g4.y;
        Gs[row][seg * 4 + 2] = g4.z; Gs[row][seg * 4 + 3] = g4.w;
    }

    f32x4 acc[4][4];
#pragma unroll
    for (int i = 0; i < 4; i++)
#pragma unroll
        for (int j = 0; j < 4; j++)
#pragma unroll
            for (int r = 0; r < 4; r++) acc[i][j][r] = 0.0f;

    for (int he = 0; he < cHE; he++) {
        f32x4 acce[4][4];
#pragma unroll
        for (int i = 0; i < 4; i++)
#pragma unroll
            for (int j = 0; j < 4; j++)
#pragma unroll
                for (int r = 0; r < 4; r++) acce[i][j][r] = 0.0f;

#pragma unroll
        for (int kc = 0; kc < 2; kc++) {
            const int ccol = (he >> 3) * 128 + kc * 64;  // physical ctx column
#pragma unroll
            for (int p = 0; p < 4; p++) {
                const int slot = p * 256 + t, row = slot >> 3, seg = slot & 7;
                *(uint4*)(As + row * 72 + seg * 8) =
                    *(const uint4*)(ctxh + (size_t)(r0 + row) * cD + ccol + seg * 8);
                *(uint4*)(Bs + row * 72 + seg * 8) =
                    *(const uint4*)(WoT + (size_t)(nt * 128 + row) * 8192 + he * 128 + kc * 64 + seg * 8);
            }
            __syncthreads();
#pragma unroll
            for (int ks = 0; ks < 64; ks += 32) {
                short8 av[4], bv[4];
#pragma unroll
                for (int i = 0; i < 4; i++)
                    av[i] = *(const short8*)(As + (wm * 64 + i * 16 + lm) * 72 + ks + quad * 8);
#pragma unroll
                for (int j = 0; j < 4; j++)
                    bv[j] = *(const short8*)(Bs + (wn * 64 + j * 16 + lm) * 72 + ks + quad * 8);
#pragma unroll
                for (int i = 0; i < 4; i++)
#pragma unroll
                    for (int j = 0; j < 4; j++)
                        acce[i][j] = __builtin_amdgcn_mfma_f32_16x16x32_bf16(av[i], bv[j], acce[i][j], 0, 0, 0);
            }
            __syncthreads();
        }
#pragma unroll
        for (int i = 0; i < 4; i++)
#pragma unroll
            for (int r = 0; r < 4; r++) {
                const float g = Gs[wm * 64 + i * 16 + quad * 4 + r][he];
#pragma unroll
                for (int j = 0; j < 4; j++) acc[i][j][r] += g * acce[i][j][r];
            }
    }
#pragma unroll
    for (int i = 0; i < 4; i++)
#pragma unroll
        for (int r = 0; r < 4; r++) {
            const int row = r0 + wm * 64 + i * 16 + quad * 4 + r;
            float* dst = out + (size_t)row * cD + nt * 128;
#pragma unroll
            for (int j = 0; j < 4; j++)
                dst[wn * 64 + j * 16 + lm] = acc[i][j][r];
        }
}

// ---------------------------------------------------------------------------
// K-QKPROJ (MFMA): q/k = x @ Wq^T / Wk^T per head. f32 out [b,h,s,dh].
// ---------------------------------------------------------------------------
__global__ __launch_bounds__(256, 2) void k_qkproj_mfma(
    const u16* __restrict__ xh, const u16* __restrict__ Wqb,
    const u16* __restrict__ Wkb, float* __restrict__ q_t, float* __restrict__ k_t)
{
    __shared__ u16 As[128 * 72];
    __shared__ u16 Bs[128 * 72];
    const int rt = blockIdx.x, nt = blockIdx.y;
    const bool isK = nt >= cH;
    const int h = isK ? nt - cH : nt;
    const u16* Wb = isK ? Wkb : Wqb;
    float* outp = isK ? k_t : q_t;
    const int r0 = rt * 128;
    const int t = threadIdx.x;
    const int w = t >> 6, lane = t & 63;
    const int wm = w >> 1, wn = w & 1;
    const int quad = lane >> 4, lm = lane & 15;

    f32x4 acc[4][4];
#pragma unroll
    for (int i = 0; i < 4; i++)
#pragma unroll
        for (int j = 0; j < 4; j++)
#pragma unroll
            for (int r = 0; r < 4; r++) acc[i][j][r] = 0.0f;

    for (int kc = 0; kc < cD; kc += 64) {
#pragma unroll
        for (int p = 0; p < 4; p++) {
            const int slot = p * 256 + t, row = slot >> 3, seg = slot & 7;
            *(uint4*)(As + row * 72 + seg * 8) =
                *(const uint4*)(xh + (size_t)(r0 + row) * cD + kc + seg * 8);
            *(uint4*)(Bs + row * 72 + seg * 8) =
                *(const uint4*)(Wb + (size_t)(h * cDH + row) * cD + kc + seg * 8);
        }
        __syncthreads();
#pragma unroll
        for (int ks = 0; ks < 64; ks += 32) {
            short8 av[4], bv[4];
#pragma unroll
            for (int i = 0; i < 4; i++)
                av[i] = *(const short8*)(As + (wm * 64 + i * 16 + lm) * 72 + ks + quad * 8);
#pragma unroll
            for (int j = 0; j < 4; j++)
                bv[j] = *(const short8*)(Bs + (wn * 64 + j * 16 + lm) * 72 + ks + quad * 8);
#pragma unroll
            for (int i = 0; i < 4; i++)
#pragma unroll
                for (int j = 0; j < 4; j++)
                    acc[i][j] = __builtin_amdgcn_mfma_f32_16x16x32_bf16(av[i], bv[j], acc[i][j], 0, 0, 0);
        }
        __syncthreads();
    }
#pragma unroll
    for (int i = 0; i < 4; i++)
#pragma unroll
        for (int r = 0; r < 4; r++) {
            const int row = r0 + wm * 64 + i * 16 + quad * 4 + r;
            const int b = row >> 11, s = row & (cS - 1);
            float* dst = outp + ((size_t)(b * cH + h) * cS + s) * cDH;
#pragma unroll
            for (int j = 0; j < 4; j++)
                dst[wn * 64 + j * 16 + lm] = acc[i][j][r];
        }
}

// ---------------------------------------------------------------------------
// RoPE + cast: read f32 q_t/k_t [b,h,s,dh], write bf16 q_b/k_b same layout.
// ---------------------------------------------------------------------------
__global__ __launch_bounds__(256) void k_rope_cast(
    const float* __restrict__ q_t, const float* __restrict__ k_t,
    const int* __restrict__ positions,
    u16* __restrict__ q_b, u16* __restrict__ k_b)
{
    const int total = cB * cH * cS * (cDH / 2);
    const int idx = blockIdx.x * 256 + threadIdx.x;
    const int which = (idx >= total) ? 1 : 0;
    const int id = which ? idx - total : idx;
    const int i = id & 63;
    const int bhs = id >> 6;
    const int s = bhs & (cS - 1);
    const int b = (bhs >> 11) >> 3;
    const float* src = (which ? k_t : q_t) + (size_t)bhs * cDH;
    u16* dst = (which ? k_b : q_b) + (size_t)bhs * cDH;
    const int pos = positions[b * cS + s];
    const float freq = powf(10000.0f, -(float)i / 64.0f);
    const float ang = (float)pos * freq;
    const float c = cosf(ang), sn = sinf(ang);
    const float t1 = src[i], t2 = src[i + 64];
    dst[i] = f2bf(t1 * c - t2 * sn);
    dst[i + 64] = f2bf(t2 * c + t1 * sn);
}

// ---------------------------------------------------------------------------
// K5: MFMA flash attention. BQ=128 (4 waves x 32 rows), BK=64, DH=128.
// Each K/V B-fragment feeds 2 MFMAs (halved LDS reads per MFMA).
// grid (16 q-tiles zigzagged, 8 h, 4 b); 2 blocks/CU (54 KB LDS).
// ---------------------------------------------------------------------------
__global__ __launch_bounds__(256, 2) void k_attn_mfma(
    const u16* __restrict__ qb, const u16* __restrict__ kb,
    const u16* __restrict__ vb, u16* __restrict__ ctxh)
{
    __shared__ u16 Ks[64][136];    // [kv][dh], 17.4 KB
    __shared__ u16 VsT[128][72];   // [dh][kv], 18.4 KB
    __shared__ u16 Ps[4][32][72];  // per-wave P strip [qrow][kv], 18.4 KB

    const int combined = blockIdx.z * 8 + blockIdx.y;  // b*8+h, 0..31
    const int qtv = (combined < 16) ? (15 - (int)blockIdx.x) : (int)blockIdx.x;
    const int h = blockIdx.y, b = blockIdx.z;
    const int q0 = qtv * 128;
    const int t = threadIdx.x;
    const int w = t >> 6, lane = t & 63;
    const int quad = lane >> 4, lm = lane & 15;
    const size_t bh = (size_t)(b * cH + h) * cS;
    const u16* kbase = kb + bh * cDH;
    const u16* vbase = vb + bh * cDH;

    // Q fragments: wave w owns rows q0+w*32 .. +31 (two 16-row m-subtiles)
    short8 aq[2][4];
#pragma unroll
    for (int mi = 0; mi < 2; mi++) {
        const u16* qrow = qb + (bh + q0 + w * 32 + mi * 16 + lm) * cDH;
#pragma unroll
        for (int ks = 0; ks < 4; ks++)
            aq[mi][ks] = *(const short8*)(qrow + ks * 32 + quad * 8);
    }

    f32x4 o_acc[2][8];
#pragma unroll
    for (int mi = 0; mi < 2; mi++)
#pragma unroll
        for (int j = 0; j < 8; j++)
#pragma unroll
            for (int r = 0; r < 4; r++) o_acc[mi][j][r] = 0.0f;
    float m_r[2][4], l_r[2][4];
#pragma unroll
    for (int mi = 0; mi < 2; mi++)
#pragma unroll
        for (int r = 0; r < 4; r++) { m_r[mi][r] = -1.0e30f; l_r[mi][r] = 0.0f; }
    const float scale = 0.08838834764831845f;  // 1/sqrt(128)
    const int nkt = 2 * qtv + 2;

    for (int kt = 0; kt < nkt; kt++) {
        const int k0 = kt * 64;
        // stage K: 64 rows x 128 dh
#pragma unroll
        for (int p = 0; p < 4; p++) {
            const int slot = p * 256 + t, row = slot >> 4, seg = slot & 15;
            *(uint4*)&Ks[row][seg * 8] =
                *(const uint4*)(kbase + (size_t)(k0 + row) * cDH + seg * 8);
        }
        // stage V transposed
        {
            const int rq = t & 15, seg = t >> 4;
            uint4 r0v = *(const uint4*)(vbase + (size_t)(k0 + rq * 4 + 0) * cDH + seg * 8);
            uint4 r1v = *(const uint4*)(vbase + (size_t)(k0 + rq * 4 + 1) * cDH + seg * 8);
            uint4 r2v = *(const uint4*)(vbase + (size_t)(k0 + rq * 4 + 2) * cDH + seg * 8);
            uint4 r3v = *(const uint4*)(vbase + (size_t)(k0 + rq * 4 + 3) * cDH + seg * 8);
            const u16* p0 = (const u16*)&r0v; const u16* p1 = (const u16*)&r1v;
            const u16* p2 = (const u16*)&r2v; const u16* p3 = (const u16*)&r3v;
#pragma unroll
            for (int jj = 0; jj < 8; jj++) {
                ushort4 val;
                val.x = p0[jj]; val.y = p1[jj]; val.z = p2[jj]; val.w = p3[jj];
                *(ushort4*)&VsT[seg * 8 + jj][rq * 4] = val;
            }
        }
        __syncthreads();

        // QK^T: 32 rows x 64 cols, shared B-fragments across the 2 m-subtiles
        f32x4 s[2][4];
#pragma unroll
        for (int mi = 0; mi < 2; mi++)
#pragma unroll
            for (int j = 0; j < 4; j++)
#pragma unroll
                for (int r = 0; r < 4; r++) s[mi][j][r] = 0.0f;
#pragma unroll
        for (int ks = 0; ks < 4; ks++) {
#pragma unroll
            for (int j = 0; j < 4; j++) {
                short8 bv = *(const short8*)&Ks[j * 16 + lm][ks * 32 + quad * 8];
                s[0][j] = __builtin_amdgcn_mfma_f32_16x16x32_bf16(aq[0][ks], bv, s[0][j], 0, 0, 0);
                s[1][j] = __builtin_amdgcn_mfma_f32_16x16x32_bf16(aq[1][ks], bv, s[1][j], 0, 0, 0);
            }
        }
        // scale + causal mask (mask needed only for the last two k-tiles)
        if (kt >= nkt - 2) {
#pragma unroll
            for (int mi = 0; mi < 2; mi++)
#pragma unroll
                for (int j = 0; j < 4; j++) {
                    const int colg = k0 + j * 16 + lm;
#pragma unroll
                    for (int r = 0; r < 4; r++) {
                        const int rowg = q0 + w * 32 + mi * 16 + quad * 4 + r;
                        s[mi][j][r] = (colg <= rowg) ? s[mi][j][r] * scale : -1.0e30f;
                    }
                }
        } else {
#pragma unroll
            for (int mi = 0; mi < 2; mi++)
#pragma unroll
                for (int j = 0; j < 4; j++)
#pragma unroll
                    for (int r = 0; r < 4; r++) s[mi][j][r] *= scale;
        }
        // online softmax per m-subtile (row stats across the quad's 16 lanes)
#pragma unroll
        for (int mi = 0; mi < 2; mi++) {
            float mt[4];
#pragma unroll
            for (int r = 0; r < 4; r++)
                mt[r] = fmaxf(fmaxf(s[mi][0][r], s[mi][1][r]), fmaxf(s[mi][2][r], s[mi][3][r]));
#pragma unroll
            for (int off = 1; off < 16; off <<= 1)
#pragma unroll
                for (int r = 0; r < 4; r++) mt[r] = fmaxf(mt[r], __shfl_xor(mt[r], off));
            float alpha[4], rs[4];
#pragma unroll
            for (int r = 0; r < 4; r++) {
                const float mn = fmaxf(m_r[mi][r], mt[r]);
                alpha[r] = __expf(m_r[mi][r] - mn);
                m_r[mi][r] = mn;
                rs[r] = 0.0f;
            }
#pragma unroll
            for (int j = 0; j < 4; j++)
#pragma unroll
                for (int r = 0; r < 4; r++) {
                    const float p = __expf(s[mi][j][r] - m_r[mi][r]);
                    s[mi][j][r] = p;
                    rs[r] += p;
                }
#pragma unroll
            for (int off = 1; off < 16; off <<= 1)
#pragma unroll
                for (int r = 0; r < 4; r++) rs[r] += __shfl_xor(rs[r], off);
#pragma unroll
            for (int r = 0; r < 4; r++) l_r[mi][r] = l_r[mi][r] * alpha[r] + rs[r];
#pragma unroll
            for (int j = 0; j < 8; j++)
#pragma unroll
                for (int r = 0; r < 4; r++) o_acc[mi][j][r] *= alpha[r];
            // P -> wave-private LDS strip
#pragma unroll
            for (int j = 0; j < 4; j++)
#pragma unroll
                for (int r = 0; r < 4; r++)
                    Ps[w][mi * 16 + quad * 4 + r][j * 16 + lm] = f2bf(s[mi][j][r]);
        }
        // PV: O[32 x 128] += P[32 x 64] * V[64 x 128], shared B-fragments
#pragma unroll
        for (int ks2 = 0; ks2 < 2; ks2++) {
            short8 ap0 = *(const short8*)&Ps[w][lm][ks2 * 32 + quad * 8];
            short8 ap1 = *(const short8*)&Ps[w][16 + lm][ks2 * 32 + quad * 8];
#pragma unroll
            for (int j2 = 0; j2 < 8; j2++) {
                short8 bv = *(const short8*)&VsT[j2 * 16 + lm][ks2 * 32 + quad * 8];
                o_acc[0][j2] = __builtin_amdgcn_mfma_f32_16x16x32_bf16(ap0, bv, o_acc[0][j2], 0, 0, 0);
                o_acc[1][j2] = __builtin_amdgcn_mfma_f32_16x16x32_bf16(ap1, bv, o_acc[1][j2], 0, 0, 0);
            }
        }
        __syncthreads();
    }
    // epilogue: ctxh [b,s,h,dh] bf16
#pragma unroll
    for (int mi = 0; mi < 2; mi++)
#pragma unroll
        for (int r = 0; r < 4; r++) {
            const float inv = 1.0f / l_r[mi][r];
            const int sg = q0 + w * 32 + mi * 16 + quad * 4 + r;
            u16* dst = ctxh + (((size_t)b * cS + sg) * cH + h) * cDH;
#pragma unroll
            for (int j2 = 0; j2 < 8; j2++)
                dst[j2 * 16 + lm] = f2bf(o_acc[mi][j2][r] * inv);
        }
}

// ---------------------------------------------------------------------------
extern "C" void kernel_launch(void* const* d_in, const int* in_sizes, int n_in,
                              void* d_out, int out_size, void* d_ws, size_t ws_size,
                              hipStream_t stream)
{
    const float* x = (const float*)d_in[0];
    const float* Wq = (const float*)d_in[1];
    const float* Wk = (const float*)d_in[2];
    const float* Wv = (const float*)d_in[3];
    const float* Wo = (const float*)d_in[4];
    const float* sel_v = (const float*)d_in[5];
    const float* sel_o = (const float*)d_in[6];
    const int* positions = (const int*)d_in[7];
    float* out = (float*)d_out;

    char* ws = (char*)d_ws;
    size_t off = 0;
    auto alloc = [&](size_t bytes) -> void* {
        void* p = ws + off;
        off += (bytes + 255) & ~(size_t)255;
        return p;
    };
    const size_t big = (size_t)cB * cH * cS * cDH * sizeof(float);  // 32 MB
    const size_t half = big / 2;                                    // 16 MB
    // Overlays (stream-ordered lifetimes):
    //   R1: WvT bf16 (ph1) -> q_t f32 (ph2)
    //   R2: k_t f32 (ph2) -> WoT bf16 (ph3)
    //   R3: [0,16M) v_b bf16; [16M,32M) Wqb+Wkb bf16 -> ctxh bf16
    //   R4: [0,16M) xh bf16 -> q_b bf16; [16M,32M) k_b bf16
    char* R1 = (char*)alloc(big);
    char* R2 = (char*)alloc(big);
    char* R3 = (char*)alloc(big);
    char* R4 = (char*)alloc(big);
    float* gv_d = (float*)alloc((size_t)cBS * 64 * sizeof(float));  // 2 MB
    float* go_d = (float*)alloc((size_t)cBS * 64 * sizeof(float));  // 2 MB

    u16* WvT = (u16*)R1;
    float* q_t = (float*)R1;
    float* k_t = (float*)R2;
    u16* WoT = (u16*)R2;
    u16* v_b = (u16*)R3;
    u16* Wqb = (u16*)(R3 + half);
    u16* Wkb = (u16*)(R3 + half + ((size_t)cD * cD * 2));
    u16* ctxh = (u16*)(R3 + half);
    u16* xh = (u16*)R4;
    u16* q_b = (u16*)R4;
    u16* k_b = (u16*)(R4 + half);

    // Phase 1: gates (f32), casts, V-expert GEMM
    k_gates<<<cBS / 8, 256, 0, stream>>>(x, sel_v, sel_o, gv_d, go_d);
    k_cast_f2b<<<8192, 256, 0, stream>>>(x, xh);
    k_cast_wv<<<dim3(16, 64), 256, 0, stream>>>(Wv, WvT);
    k_gemm_v<<<dim3(64, 8), 256, 0, stream>>>(xh, WvT, gv_d, v_b);

    // Phase 2: Q/K projection (MFMA) + RoPE-cast + MFMA attention
    k_cast_f2b<<<1024, 256, 0, stream>>>(Wq, Wqb);
    k_cast_f2b<<<1024, 256, 0, stream>>>(Wk, Wkb);
    k_qkproj_mfma<<<dim3(64, 16), 256, 0, stream>>>(xh, Wqb, Wkb, q_t, k_t);
    k_rope_cast<<<(2 * cB * cH * cS * (cDH / 2)) / 256, 256, 0, stream>>>(
        q_t, k_t, positions, q_b, k_b);
    k_attn_mfma<<<dim3(16, 8, 4), 256, 0, stream>>>(q_b, k_b, v_b, ctxh);

    // Phase 3: O-expert GEMM
    k_cast_wo<<<dim3(16, 64), 256, 0, stream>>>(Wo, WoT);
    k_gemm_o<<<dim3(64, 8), 256, 0, stream>>>(ctxh, WoT, go_d, out);
}

// Round 9
// 725.422 us; speedup vs baseline: 9.8665x; 1.2040x over previous
//
#include <hip/hip_runtime.h>
#include <math.h>

typedef unsigned short u16;
typedef unsigned int u32;
typedef __attribute__((ext_vector_type(8))) short short8;  // 8 bf16 (4 VGPRs)
typedef __attribute__((ext_vector_type(4))) float f32x4;   // MFMA C/D

// Problem constants
constexpr int cB = 4, cS = 2048, cD = 1024, cH = 8, cE = 8, cK = 2, cDH = 128;
constexpr int cBS = cB * cS;          // 8192
constexpr int cHE = cH * cE;          // 64

__device__ inline u16 f2bf(float f) {
    u32 u = __float_as_uint(f);
    u += 0x7fffu + ((u >> 16) & 1u);   // RNE
    return (u16)(u >> 16);
}
__device__ inline float bf2f(u16 h) { return __uint_as_float(((u32)h) << 16); }

// ---------------------------------------------------------------------------
// Split cast: f32 -> bf16 hi + bf16 lo (lo = RNE(x - hi)). hi doubles as the
// plain bf16 cast for the rest of the pipeline.
// ---------------------------------------------------------------------------
__global__ __launch_bounds__(256) void k_cast_split(
    const float* __restrict__ src, u16* __restrict__ hi, u16* __restrict__ lo)
{
    const size_t i = (size_t)blockIdx.x * 256 + threadIdx.x;  // float4 index
    float4 v = ((const float4*)src)[i];
    u16 hx = f2bf(v.x), hy = f2bf(v.y), hz = f2bf(v.z), hw = f2bf(v.w);
    u16 lx = f2bf(v.x - bf2f(hx)), ly = f2bf(v.y - bf2f(hy));
    u16 lz = f2bf(v.z - bf2f(hz)), lw = f2bf(v.w - bf2f(hw));
    uint2 oh; oh.x = (u32)hx | ((u32)hy << 16); oh.y = (u32)hz | ((u32)hw << 16);
    uint2 ol; ol.x = (u32)lx | ((u32)ly << 16); ol.y = (u32)lz | ((u32)lw << 16);
    ((uint2*)hi)[i] = oh;
    ((uint2*)lo)[i] = ol;
}

// ---------------------------------------------------------------------------
// Logits GEMM, bf16x3: lgp[t][8192][128] partials, t in {hi.hi, lo.hi, hi.lo}.
// Sum of the 3 partials ~ f32 logits (error ~7e-6 << tie threshold 1e-3).
// grid (64 row-tiles, 3 terms).
// ---------------------------------------------------------------------------
__global__ __launch_bounds__(256, 2) void k_gemm_logits3(
    const u16* __restrict__ xh, const u16* __restrict__ xlo,
    const u16* __restrict__ selh, const u16* __restrict__ sell,
    float* __restrict__ lgp)
{
    __shared__ u16 As[128 * 72];
    __shared__ u16 Bs[128 * 72];
    const int r0 = blockIdx.x * 128;
    const int term = blockIdx.y;
    const u16* A = (term == 1) ? xlo : xh;
    const u16* B = (term == 2) ? sell : selh;
    float* outp = lgp + (size_t)term * cBS * 128;
    const int t = threadIdx.x;
    const int w = t >> 6, lane = t & 63;
    const int wm = w >> 1, wn = w & 1;
    const int quad = lane >> 4, lm = lane & 15;

    f32x4 acc[4][4];
#pragma unroll
    for (int i = 0; i < 4; i++)
#pragma unroll
        for (int j = 0; j < 4; j++)
#pragma unroll
            for (int r = 0; r < 4; r++) acc[i][j][r] = 0.0f;

    for (int kc = 0; kc < cD; kc += 64) {
#pragma unroll
        for (int p = 0; p < 4; p++) {
            const int slot = p * 256 + t, row = slot >> 3, seg = slot & 7;
            *(uint4*)(As + row * 72 + seg * 8) =
                *(const uint4*)(A + (size_t)(r0 + row) * cD + kc + seg * 8);
            *(uint4*)(Bs + row * 72 + seg * 8) =
                *(const uint4*)(B + (size_t)row * cD + kc + seg * 8);
        }
        __syncthreads();
#pragma unroll
        for (int ks = 0; ks < 64; ks += 32) {
            short8 av[4], bv[4];
#pragma unroll
            for (int i = 0; i < 4; i++)
                av[i] = *(const short8*)(As + (wm * 64 + i * 16 + lm) * 72 + ks + quad * 8);
#pragma unroll
            for (int j = 0; j < 4; j++)
                bv[j] = *(const short8*)(Bs + (wn * 64 + j * 16 + lm) * 72 + ks + quad * 8);
#pragma unroll
            for (int i = 0; i < 4; i++)
#pragma unroll
                for (int j = 0; j < 4; j++)
                    acc[i][j] = __builtin_amdgcn_mfma_f32_16x16x32_bf16(av[i], bv[j], acc[i][j], 0, 0, 0);
        }
        __syncthreads();
    }
#pragma unroll
    for (int i = 0; i < 4; i++)
#pragma unroll
        for (int r = 0; r < 4; r++) {
            const int row = r0 + wm * 64 + i * 16 + quad * 4 + r;
#pragma unroll
            for (int j = 0; j < 4; j++)
                outp[(size_t)row * 128 + wn * 64 + j * 16 + lm] = acc[i][j][r];
        }
}

// ---------------------------------------------------------------------------
// Top-2 + sigmoid from summed partials -> dense gates; flag near-ties at the
// #2/#3 boundary (gap < 1e-3) for exact-f32 repair. 131072 threads.
// ---------------------------------------------------------------------------
__global__ __launch_bounds__(256) void k_top2_flag(
    const float* __restrict__ lgp, float* __restrict__ gv_d, float* __restrict__ go_d,
    int* __restrict__ flags, int* __restrict__ counter)
{
    const int idx = blockIdx.x * 256 + threadIdx.x;
    const int row = idx >> 4, r16 = idx & 15;
    const int which = r16 >> 3, h = r16 & 7;
    const float* l0 = lgp + (size_t)row * 128 + which * 64 + h * 8;
    const float* l1 = l0 + (size_t)cBS * 128;
    const float* l2 = l1 + (size_t)cBS * 128;
    float v[8];
#pragma unroll
    for (int e = 0; e < cE; e++) v[e] = l0[e] + l1[e] + l2[e];
    int i0 = 0; float b0 = v[0];
#pragma unroll
    for (int e = 1; e < cE; e++) { if (v[e] > b0) { b0 = v[e]; i0 = e; } }
    int i1 = -1; float b1 = -3.0e38f;
#pragma unroll
    for (int e = 0; e < cE; e++) { if (e != i0 && v[e] > b1) { b1 = v[e]; i1 = e; } }
    float b2 = -3.0e38f;
#pragma unroll
    for (int e = 0; e < cE; e++) { if (e != i0 && e != i1 && v[e] > b2) b2 = v[e]; }
    const float w0 = 1.0f / (1.0f + __expf(-b0));
    const float w1 = 1.0f / (1.0f + __expf(-b1));
    float* dst = (which ? go_d : gv_d) + (size_t)row * 64 + h * 8;
#pragma unroll
    for (int e = 0; e < cE; e++)
        dst[e] = (e == i0) ? w0 : ((e == i1) ? w1 : 0.0f);
    if (b1 - b2 < 1.0e-3f) {
        const int s = atomicAdd(counter, 1);
        flags[s] = (row << 4) | r16;
    }
}

// ---------------------------------------------------------------------------
// Repair: exact-f32 logits for flagged near-tie rows; overwrite gate row.
// One wave per item, grid-stride over the device-side count.
// ---------------------------------------------------------------------------
__global__ __launch_bounds__(64) void k_repair(
    const float* __restrict__ x, const float* __restrict__ sel_v,
    const float* __restrict__ sel_o,
    const int* __restrict__ counter, const int* __restrict__ flags,
    float* __restrict__ gv_d, float* __restrict__ go_d)
{
    const int n = *counter;
    const int lane = threadIdx.x;
    for (int it = blockIdx.x; it < n; it += gridDim.x) {
        const int item = flags[it];
        const int row = item >> 4, which = (item >> 3) & 1, h = item & 7;
        const float* xr = x + (size_t)row * cD;
        const float* sb = (which ? sel_o : sel_v) + (size_t)(h * 8) * cD;
        float lg[8];
#pragma unroll
        for (int e = 0; e < cE; e++) {
            float a = 0.0f;
#pragma unroll
            for (int dg = 0; dg < 4; dg++) {
                const int d = dg * 256 + lane * 4;
                const float4 xv = *(const float4*)(xr + d);
                const float4 sv = *(const float4*)(sb + (size_t)e * cD + d);
                a += xv.x * sv.x + xv.y * sv.y + xv.z * sv.z + xv.w * sv.w;
            }
#pragma unroll
            for (int off = 1; off < 64; off <<= 1) a += __shfl_xor(a, off);
            lg[e] = a;
        }
        int i0 = 0; float b0 = lg[0];
#pragma unroll
        for (int e = 1; e < cE; e++) { if (lg[e] > b0) { b0 = lg[e]; i0 = e; } }
        int i1 = -1; float b1 = -3.0e38f;
#pragma unroll
        for (int e = 0; e < cE; e++) { if (e != i0 && lg[e] > b1) { b1 = lg[e]; i1 = e; } }
        if (lane == 0) {
            const float w0 = 1.0f / (1.0f + expf(-b0));
            const float w1 = 1.0f / (1.0f + expf(-b1));
            float* dst = (which ? go_d : gv_d) + (size_t)row * 64 + h * 8;
#pragma unroll
            for (int e = 0; e < cE; e++)
                dst[e] = (e == i0) ? w0 : ((e == i1) ? w1 : 0.0f);
        }
    }
}

// ---------------------------------------------------------------------------
// Elementwise f32 -> bf16 cast (weights). grid = nfloat4/256 blocks x 256.
// ---------------------------------------------------------------------------
__global__ __launch_bounds__(256) void k_cast_f2b(
    const float* __restrict__ src, u16* __restrict__ dst)
{
    const size_t i = (size_t)blockIdx.x * 256 + threadIdx.x;  // float4 index
    float4 v = ((const float4*)src)[i];
    u32 lo = (u32)f2bf(v.x) | ((u32)f2bf(v.y) << 16);
    u32 hi = (u32)f2bf(v.z) | ((u32)f2bf(v.w) << 16);
    uint2 o; o.x = lo; o.y = hi;
    ((uint2*)dst)[i] = o;
}

// ---------------------------------------------------------------------------
// Transpose-cast Wv [HE][D][DH] f32 -> WvT [(he*128+dh)][d] bf16.
// ---------------------------------------------------------------------------
__global__ __launch_bounds__(256) void k_cast_wv(
    const float* __restrict__ Wv, u16* __restrict__ WvT)
{
    __shared__ float ld[64][132];  // [d-local][dh]
    const int d0 = blockIdx.x * 64, he = blockIdx.y;
    const int t = threadIdx.x;
    for (int p = 0; p < 8; p++) {
        const int slot = p * 256 + t, r = slot >> 5, c4 = slot & 31;
        float4 v = *(const float4*)(Wv + ((size_t)he * cD + d0 + r) * cDH + c4 * 4);
        ld[r][c4 * 4 + 0] = v.x; ld[r][c4 * 4 + 1] = v.y;
        ld[r][c4 * 4 + 2] = v.z; ld[r][c4 * 4 + 3] = v.w;
    }
    __syncthreads();
    for (int p = 0; p < 16; p++) {
        const int slot = p * 256 + t, dh = slot >> 5, c2 = slot & 31;
        u32 val = (u32)f2bf(ld[c2 * 2 + 0][dh]) | ((u32)f2bf(ld[c2 * 2 + 1][dh]) << 16);
        *(u32*)(WvT + (size_t)(he * cDH + dh) * cD + d0 + c2 * 2) = val;
    }
}

// ---------------------------------------------------------------------------
// Transpose-cast Wo [HE][DH][D] f32 -> WoT [m][(he*128+dh)] bf16.
// ---------------------------------------------------------------------------
__global__ __launch_bounds__(256) void k_cast_wo(
    const float* __restrict__ Wo, u16* __restrict__ WoT)
{
    __shared__ float ld[128][68];  // [dh][m-local]
    const int m0 = blockIdx.x * 64, he = blockIdx.y;
    const int t = threadIdx.x;
    for (int p = 0; p < 8; p++) {
        const int slot = p * 256 + t, r = slot >> 4, c4 = slot & 15;
        float4 v = *(const float4*)(Wo + ((size_t)he * cDH + r) * cD + m0 + c4 * 4);
        ld[r][c4 * 4 + 0] = v.x; ld[r][c4 * 4 + 1] = v.y;
        ld[r][c4 * 4 + 2] = v.z; ld[r][c4 * 4 + 3] = v.w;
    }
    __syncthreads();
    for (int p = 0; p < 16; p++) {
        const int slot = p * 256 + t, mr = slot >> 6, c2 = slot & 63;
        u32 val = (u32)f2bf(ld[c2 * 2 + 0][mr]) | ((u32)f2bf(ld[c2 * 2 + 1][mr]) << 16);
        *(u32*)(WoT + (size_t)(m0 + mr) * 8192 + he * cDH + c2 * 2) = val;
    }
}

// ---------------------------------------------------------------------------
// K-GEMM-V: v_b[b,h,s,:] = sum_e gv[bs,h,e]*(x[bs,:] @ Wv[h,e])  (bf16 out)
// ---------------------------------------------------------------------------
__global__ __launch_bounds__(256, 2) void k_gemm_v(
    const u16* __restrict__ xh, const u16* __restrict__ WvT,
    const float* __restrict__ gv_d, u16* __restrict__ v_b)
{
    __shared__ u16 As[128 * 72];
    __shared__ u16 Bs[128 * 72];
    __shared__ float Gs[128][9];   // [row][e], +1 pad
    const int rt = blockIdx.x, h = blockIdx.y;
    const int r0 = rt * 128;
    const int t = threadIdx.x;
    const int w = t >> 6, lane = t & 63;
    const int wm = w >> 1, wn = w & 1;
    const int quad = lane >> 4, lm = lane & 15;

    {
        const int row = t >> 1, half = t & 1;
        float4 g4 = *(const float4*)(gv_d + (size_t)(r0 + row) * 64 + h * 8 + half * 4);
        Gs[row][half * 4 + 0] = g4.x; Gs[row][half * 4 + 1] = g4.y;
        Gs[row][half * 4 + 2] = g4.z; Gs[row][half * 4 + 3] = g4.w;
    }

    f32x4 acc[4][4];
#pragma unroll
    for (int i = 0; i < 4; i++)
#pragma unroll
        for (int j = 0; j < 4; j++)
#pragma unroll
            for (int r = 0; r < 4; r++) acc[i][j][r] = 0.0f;

    for (int e = 0; e < cE; e++) {
        f32x4 acce[4][4];
#pragma unroll
        for (int i = 0; i < 4; i++)
#pragma unroll
            for (int j = 0; j < 4; j++)
#pragma unroll
                for (int r = 0; r < 4; r++) acce[i][j][r] = 0.0f;

        for (int kc = 0; kc < cD; kc += 64) {
#pragma unroll
            for (int p = 0; p < 4; p++) {
                const int slot = p * 256 + t, row = slot >> 3, seg = slot & 7;
                *(uint4*)(As + row * 72 + seg * 8) =
                    *(const uint4*)(xh + (size_t)(r0 + row) * cD + kc + seg * 8);
                *(uint4*)(Bs + row * 72 + seg * 8) =
                    *(const uint4*)(WvT + (size_t)((h * 8 + e) * cDH + row) * cD + kc + seg * 8);
            }
            __syncthreads();
#pragma unroll
            for (int ks = 0; ks < 64; ks += 32) {
                short8 av[4], bv[4];
#pragma unroll
                for (int i = 0; i < 4; i++)
                    av[i] = *(const short8*)(As + (wm * 64 + i * 16 + lm) * 72 + ks + quad * 8);
#pragma unroll
                for (int j = 0; j < 4; j++)
                    bv[j] = *(const short8*)(Bs + (wn * 64 + j * 16 + lm) * 72 + ks + quad * 8);
#pragma unroll
                for (int i = 0; i < 4; i++)
#pragma unroll
                    for (int j = 0; j < 4; j++)
                        acce[i][j] = __builtin_amdgcn_mfma_f32_16x16x32_bf16(av[i], bv[j], acce[i][j], 0, 0, 0);
            }
            __syncthreads();
        }
#pragma unroll
        for (int i = 0; i < 4; i++)
#pragma unroll
            for (int r = 0; r < 4; r++) {
                const float g = Gs[wm * 64 + i * 16 + quad * 4 + r][e];
#pragma unroll
                for (int j = 0; j < 4; j++) acc[i][j][r] += g * acce[i][j][r];
            }
    }
#pragma unroll
    for (int i = 0; i < 4; i++)
#pragma unroll
        for (int r = 0; r < 4; r++) {
            const int row = r0 + wm * 64 + i * 16 + quad * 4 + r;
            const int b = row >> 11, s = row & (cS - 1);
            u16* dst = v_b + ((size_t)(b * cH + h) * cS + s) * cDH;
#pragma unroll
            for (int j = 0; j < 4; j++)
                dst[wn * 64 + j * 16 + lm] = f2bf(acc[i][j][r]);
        }
}

// ---------------------------------------------------------------------------
// K-GEMM-O: out[bs,:] = sum_{h,e} go[bs,h,e]*(ctx[bs,h,:] @ Wo[h,e])
// ---------------------------------------------------------------------------
__global__ __launch_bounds__(256, 2) void k_gemm_o(
    const u16* __restrict__ ctxh, const u16* __restrict__ WoT,
    const float* __restrict__ go_d, float* __restrict__ out)
{
    __shared__ u16 As[128 * 72];
    __shared__ u16 Bs[128 * 72];
    __shared__ float Gs[128][65];  // [row][he], +1 pad (33 KB)
    const int rt = blockIdx.x, nt = blockIdx.y;
    const int r0 = rt * 128;
    const int t = threadIdx.x;
    const int w = t >> 6, lane = t & 63;
    const int wm = w >> 1, wn = w & 1;
    const int quad = lane >> 4, lm = lane & 15;

#pragma unroll
    for (int p = 0; p < 8; p++) {
        const int slot = p * 256 + t, row = slot >> 4, seg = slot & 15;
        float4 g4 = *(const float4*)(go_d + (size_t)(r0 + row) * 64 + seg * 4);
        Gs[row][seg * 4 + 0] = g4.x; Gs[row][seg * 4 + 1] = g4.y;
        Gs[row][seg * 4 + 2] = g4.z; Gs[row][seg * 4 + 3] = g4.w;
    }

    f32x4 acc[4][4];
#pragma unroll
    for (int i = 0; i < 4; i++)
#pragma unroll
        for (int j = 0; j < 4; j++)
#pragma unroll
            for (int r = 0; r < 4; r++) acc[i][j][r] = 0.0f;

    for (int he = 0; he < cHE; he++) {
        f32x4 acce[4][4];
#pragma unroll
        for (int i = 0; i < 4; i++)
#pragma unroll
            for (int j = 0; j < 4; j++)
#pragma unroll
                for (int r = 0; r < 4; r++) acce[i][j][r] = 0.0f;

#pragma unroll
        for (int kc = 0; kc < 2; kc++) {
            const int ccol = (he >> 3) * 128 + kc * 64;  // physical ctx column
#pragma unroll
            for (int p = 0; p < 4; p++) {
                const int slot = p * 256 + t, row = slot >> 3, seg = slot & 7;
                *(uint4*)(As + row * 72 + seg * 8) =
                    *(const uint4*)(ctxh + (size_t)(r0 + row) * cD + ccol + seg * 8);
                *(uint4*)(Bs + row * 72 + seg * 8) =
                    *(const uint4*)(WoT + (size_t)(nt * 128 + row) * 8192 + he * 128 + kc * 64 + seg * 8);
            }
            __syncthreads();
#pragma unroll
            for (int ks = 0; ks < 64; ks += 32) {
                short8 av[4], bv[4];
#pragma unroll
                for (int i = 0; i < 4; i++)
                    av[i] = *(const short8*)(As + (wm * 64 + i * 16 + lm) * 72 + ks + quad * 8);
#pragma unroll
                for (int j = 0; j < 4; j++)
                    bv[j] = *(const short8*)(Bs + (wn * 64 + j * 16 + lm) * 72 + ks + quad * 8);
#pragma unroll
                for (int i = 0; i < 4; i++)
#pragma unroll
                    for (int j = 0; j < 4; j++)
                        acce[i][j] = __builtin_amdgcn_mfma_f32_16x16x32_bf16(av[i], bv[j], acce[i][j], 0, 0, 0);
            }
            __syncthreads();
        }
#pragma unroll
        for (int i = 0; i < 4; i++)
#pragma unroll
            for (int r = 0; r < 4; r++) {
                const float g = Gs[wm * 64 + i * 16 + quad * 4 + r][he];
#pragma unroll
                for (int j = 0; j < 4; j++) acc[i][j][r] += g * acce[i][j][r];
            }
    }
#pragma unroll
    for (int i = 0; i < 4; i++)
#pragma unroll
        for (int r = 0; r < 4; r++) {
            const int row = r0 + wm * 64 + i * 16 + quad * 4 + r;
            float* dst = out + (size_t)row * cD + nt * 128;
#pragma unroll
            for (int j = 0; j < 4; j++)
                dst[wn * 64 + j * 16 + lm] = acc[i][j][r];
        }
}

// ---------------------------------------------------------------------------
// K-QKPROJ (MFMA): q/k = x @ Wq^T / Wk^T per head. f32 out [b,h,s,dh].
// ---------------------------------------------------------------------------
__global__ __launch_bounds__(256, 2) void k_qkproj_mfma(
    const u16* __restrict__ xh, const u16* __restrict__ Wqb,
    const u16* __restrict__ Wkb, float* __restrict__ q_t, float* __restrict__ k_t)
{
    __shared__ u16 As[128 * 72];
    __shared__ u16 Bs[128 * 72];
    const int rt = blockIdx.x, nt = blockIdx.y;
    const bool isK = nt >= cH;
    const int h = isK ? nt - cH : nt;
    const u16* Wb = isK ? Wkb : Wqb;
    float* outp = isK ? k_t : q_t;
    const int r0 = rt * 128;
    const int t = threadIdx.x;
    const int w = t >> 6, lane = t & 63;
    const int wm = w >> 1, wn = w & 1;
    const int quad = lane >> 4, lm = lane & 15;

    f32x4 acc[4][4];
#pragma unroll
    for (int i = 0; i < 4; i++)
#pragma unroll
        for (int j = 0; j < 4; j++)
#pragma unroll
            for (int r = 0; r < 4; r++) acc[i][j][r] = 0.0f;

    for (int kc = 0; kc < cD; kc += 64) {
#pragma unroll
        for (int p = 0; p < 4; p++) {
            const int slot = p * 256 + t, row = slot >> 3, seg = slot & 7;
            *(uint4*)(As + row * 72 + seg * 8) =
                *(const uint4*)(xh + (size_t)(r0 + row) * cD + kc + seg * 8);
            *(uint4*)(Bs + row * 72 + seg * 8) =
                *(const uint4*)(Wb + (size_t)(h * cDH + row) * cD + kc + seg * 8);
        }
        __syncthreads();
#pragma unroll
        for (int ks = 0; ks < 64; ks += 32) {
            short8 av[4], bv[4];
#pragma unroll
            for (int i = 0; i < 4; i++)
                av[i] = *(const short8*)(As + (wm * 64 + i * 16 + lm) * 72 + ks + quad * 8);
#pragma unroll
            for (int j = 0; j < 4; j++)
                bv[j] = *(const short8*)(Bs + (wn * 64 + j * 16 + lm) * 72 + ks + quad * 8);
#pragma unroll
            for (int i = 0; i < 4; i++)
#pragma unroll
                for (int j = 0; j < 4; j++)
                    acc[i][j] = __builtin_amdgcn_mfma_f32_16x16x32_bf16(av[i], bv[j], acc[i][j], 0, 0, 0);
        }
        __syncthreads();
    }
#pragma unroll
    for (int i = 0; i < 4; i++)
#pragma unroll
        for (int r = 0; r < 4; r++) {
            const int row = r0 + wm * 64 + i * 16 + quad * 4 + r;
            const int b = row >> 11, s = row & (cS - 1);
            float* dst = outp + ((size_t)(b * cH + h) * cS + s) * cDH;
#pragma unroll
            for (int j = 0; j < 4; j++)
                dst[wn * 64 + j * 16 + lm] = acc[i][j][r];
        }
}

// ---------------------------------------------------------------------------
// RoPE + cast: read f32 q_t/k_t [b,h,s,dh], write bf16 q_b/k_b same layout.
// ---------------------------------------------------------------------------
__global__ __launch_bounds__(256) void k_rope_cast(
    const float* __restrict__ q_t, const float* __restrict__ k_t,
    const int* __restrict__ positions,
    u16* __restrict__ q_b, u16* __restrict__ k_b)
{
    const int total = cB * cH * cS * (cDH / 2);
    const int idx = blockIdx.x * 256 + threadIdx.x;
    const int which = (idx >= total) ? 1 : 0;
    const int id = which ? idx - total : idx;
    const int i = id & 63;
    const int bhs = id >> 6;
    const int s = bhs & (cS - 1);
    const int b = (bhs >> 11) >> 3;
    const float* src = (which ? k_t : q_t) + (size_t)bhs * cDH;
    u16* dst = (which ? k_b : q_b) + (size_t)bhs * cDH;
    const int pos = positions[b * cS + s];
    const float freq = powf(10000.0f, -(float)i / 64.0f);
    const float ang = (float)pos * freq;
    const float c = cosf(ang), sn = sinf(ang);
    const float t1 = src[i], t2 = src[i + 64];
    dst[i] = f2bf(t1 * c - t2 * sn);
    dst[i + 64] = f2bf(t2 * c + t1 * sn);
}

// ---------------------------------------------------------------------------
// K5: MFMA flash attention. BQ=128 (4 waves x 32 rows), BK=64, DH=128.
// ---------------------------------------------------------------------------
__global__ __launch_bounds__(256, 2) void k_attn_mfma(
    const u16* __restrict__ qb, const u16* __restrict__ kb,
    const u16* __restrict__ vb, u16* __restrict__ ctxh)
{
    __shared__ u16 Ks[64][136];    // [kv][dh], 17.4 KB
    __shared__ u16 VsT[128][72];   // [dh][kv], 18.4 KB
    __shared__ u16 Ps[4][32][72];  // per-wave P strip [qrow][kv], 18.4 KB

    const int combined = blockIdx.z * 8 + blockIdx.y;  // b*8+h, 0..31
    const int qtv = (combined < 16) ? (15 - (int)blockIdx.x) : (int)blockIdx.x;
    const int h = blockIdx.y, b = blockIdx.z;
    const int q0 = qtv * 128;
    const int t = threadIdx.x;
    const int w = t >> 6, lane = t & 63;
    const int quad = lane >> 4, lm = lane & 15;
    const size_t bh = (size_t)(b * cH + h) * cS;
    const u16* kbase = kb + bh * cDH;
    const u16* vbase = vb + bh * cDH;

    short8 aq[2][4];
#pragma unroll
    for (int mi = 0; mi < 2; mi++) {
        const u16* qrow = qb + (bh + q0 + w * 32 + mi * 16 + lm) * cDH;
#pragma unroll
        for (int ks = 0; ks < 4; ks++)
            aq[mi][ks] = *(const short8*)(qrow + ks * 32 + quad * 8);
    }

    f32x4 o_acc[2][8];
#pragma unroll
    for (int mi = 0; mi < 2; mi++)
#pragma unroll
        for (int j = 0; j < 8; j++)
#pragma unroll
            for (int r = 0; r < 4; r++) o_acc[mi][j][r] = 0.0f;
    float m_r[2][4], l_r[2][4];
#pragma unroll
    for (int mi = 0; mi < 2; mi++)
#pragma unroll
        for (int r = 0; r < 4; r++) { m_r[mi][r] = -1.0e30f; l_r[mi][r] = 0.0f; }
    const float scale = 0.08838834764831845f;  // 1/sqrt(128)
    const int nkt = 2 * qtv + 2;

    for (int kt = 0; kt < nkt; kt++) {
        const int k0 = kt * 64;
#pragma unroll
        for (int p = 0; p < 4; p++) {
            const int slot = p * 256 + t, row = slot >> 4, seg = slot & 15;
            *(uint4*)&Ks[row][seg * 8] =
                *(const uint4*)(kbase + (size_t)(k0 + row) * cDH + seg * 8);
        }
        {
            const int rq = t & 15, seg = t >> 4;
            uint4 r0v = *(const uint4*)(vbase + (size_t)(k0 + rq * 4 + 0) * cDH + seg * 8);
            uint4 r1v = *(const uint4*)(vbase + (size_t)(k0 + rq * 4 + 1) * cDH + seg * 8);
            uint4 r2v = *(const uint4*)(vbase + (size_t)(k0 + rq * 4 + 2) * cDH + seg * 8);
            uint4 r3v = *(const uint4*)(vbase + (size_t)(k0 + rq * 4 + 3) * cDH + seg * 8);
            const u16* p0 = (const u16*)&r0v; const u16* p1 = (const u16*)&r1v;
            const u16* p2 = (const u16*)&r2v; const u16* p3 = (const u16*)&r3v;
#pragma unroll
            for (int jj = 0; jj < 8; jj++) {
                ushort4 val;
                val.x = p0[jj]; val.y = p1[jj]; val.z = p2[jj]; val.w = p3[jj];
                *(ushort4*)&VsT[seg * 8 + jj][rq * 4] = val;
            }
        }
        __syncthreads();

        f32x4 s[2][4];
#pragma unroll
        for (int mi = 0; mi < 2; mi++)
#pragma unroll
            for (int j = 0; j < 4; j++)
#pragma unroll
                for (int r = 0; r < 4; r++) s[mi][j][r] = 0.0f;
#pragma unroll
        for (int ks = 0; ks < 4; ks++) {
#pragma unroll
            for (int j = 0; j < 4; j++) {
                short8 bv = *(const short8*)&Ks[j * 16 + lm][ks * 32 + quad * 8];
                s[0][j] = __builtin_amdgcn_mfma_f32_16x16x32_bf16(aq[0][ks], bv, s[0][j], 0, 0, 0);
                s[1][j] = __builtin_amdgcn_mfma_f32_16x16x32_bf16(aq[1][ks], bv, s[1][j], 0, 0, 0);
            }
        }
        if (kt >= nkt - 2) {
#pragma unroll
            for (int mi = 0; mi < 2; mi++)
#pragma unroll
                for (int j = 0; j < 4; j++) {
                    const int colg = k0 + j * 16 + lm;
#pragma unroll
                    for (int r = 0; r < 4; r++) {
                        const int rowg = q0 + w * 32 + mi * 16 + quad * 4 + r;
                        s[mi][j][r] = (colg <= rowg) ? s[mi][j][r] * scale : -1.0e30f;
                    }
                }
        } else {
#pragma unroll
            for (int mi = 0; mi < 2; mi++)
#pragma unroll
                for (int j = 0; j < 4; j++)
#pragma unroll
                    for (int r = 0; r < 4; r++) s[mi][j][r] *= scale;
        }
#pragma unroll
        for (int mi = 0; mi < 2; mi++) {
            float mt[4];
#pragma unroll
            for (int r = 0; r < 4; r++)
                mt[r] = fmaxf(fmaxf(s[mi][0][r], s[mi][1][r]), fmaxf(s[mi][2][r], s[mi][3][r]));
#pragma unroll
            for (int off = 1; off < 16; off <<= 1)
#pragma unroll
                for (int r = 0; r < 4; r++) mt[r] = fmaxf(mt[r], __shfl_xor(mt[r], off));
            float alpha[4], rs[4];
#pragma unroll
            for (int r = 0; r < 4; r++) {
                const float mn = fmaxf(m_r[mi][r], mt[r]);
                alpha[r] = __expf(m_r[mi][r] - mn);
                m_r[mi][r] = mn;
                rs[r] = 0.0f;
            }
#pragma unroll
            for (int j = 0; j < 4; j++)
#pragma unroll
                for (int r = 0; r < 4; r++) {
                    const float p = __expf(s[mi][j][r] - m_r[mi][r]);
                    s[mi][j][r] = p;
                    rs[r] += p;
                }
#pragma unroll
            for (int off = 1; off < 16; off <<= 1)
#pragma unroll
                for (int r = 0; r < 4; r++) rs[r] += __shfl_xor(rs[r], off);
#pragma unroll
            for (int r = 0; r < 4; r++) l_r[mi][r] = l_r[mi][r] * alpha[r] + rs[r];
#pragma unroll
            for (int j = 0; j < 8; j++)
#pragma unroll
                for (int r = 0; r < 4; r++) o_acc[mi][j][r] *= alpha[r];
#pragma unroll
            for (int j = 0; j < 4; j++)
#pragma unroll
                for (int r = 0; r < 4; r++)
                    Ps[w][mi * 16 + quad * 4 + r][j * 16 + lm] = f2bf(s[mi][j][r]);
        }
#pragma unroll
        for (int ks2 = 0; ks2 < 2; ks2++) {
            short8 ap0 = *(const short8*)&Ps[w][lm][ks2 * 32 + quad * 8];
            short8 ap1 = *(const short8*)&Ps[w][16 + lm][ks2 * 32 + quad * 8];
#pragma unroll
            for (int j2 = 0; j2 < 8; j2++) {
                short8 bv = *(const short8*)&VsT[j2 * 16 + lm][ks2 * 32 + quad * 8];
                o_acc[0][j2] = __builtin_amdgcn_mfma_f32_16x16x32_bf16(ap0, bv, o_acc[0][j2], 0, 0, 0);
                o_acc[1][j2] = __builtin_amdgcn_mfma_f32_16x16x32_bf16(ap1, bv, o_acc[1][j2], 0, 0, 0);
            }
        }
        __syncthreads();
    }
#pragma unroll
    for (int mi = 0; mi < 2; mi++)
#pragma unroll
        for (int r = 0; r < 4; r++) {
            const float inv = 1.0f / l_r[mi][r];
            const int sg = q0 + w * 32 + mi * 16 + quad * 4 + r;
            u16* dst = ctxh + (((size_t)b * cS + sg) * cH + h) * cDH;
#pragma unroll
            for (int j2 = 0; j2 < 8; j2++)
                dst[j2 * 16 + lm] = f2bf(o_acc[mi][j2][r] * inv);
        }
}

// ---------------------------------------------------------------------------
extern "C" void kernel_launch(void* const* d_in, const int* in_sizes, int n_in,
                              void* d_out, int out_size, void* d_ws, size_t ws_size,
                              hipStream_t stream)
{
    const float* x = (const float*)d_in[0];
    const float* Wq = (const float*)d_in[1];
    const float* Wk = (const float*)d_in[2];
    const float* Wv = (const float*)d_in[3];
    const float* Wo = (const float*)d_in[4];
    const float* sel_v = (const float*)d_in[5];
    const float* sel_o = (const float*)d_in[6];
    const int* positions = (const int*)d_in[7];
    float* out = (float*)d_out;

    char* ws = (char*)d_ws;
    size_t off = 0;
    auto alloc = [&](size_t bytes) -> void* {
        void* p = ws + off;
        off += (bytes + 255) & ~(size_t)255;
        return p;
    };
    const size_t big = (size_t)cB * cH * cS * cDH * sizeof(float);  // 32 MB
    const size_t half = big / 2;                                    // 16 MB
    // Overlays (stream-ordered lifetimes):
    //   R1: [0:16M) WvT bf16; [16:28M) lgp f32 partials -> q_t f32 (ph2)
    //   R2: [0:16M) xlo bf16 -> k_t f32 (ph2) -> WoT bf16 (ph3)
    //   R3: [0,16M) v_b bf16; [16M,32M) Wqb+Wkb bf16 -> ctxh bf16
    //   R4: [0,16M) xh bf16 -> q_b bf16; [16M,32M) k_b bf16
    char* R1 = (char*)alloc(big);
    char* R2 = (char*)alloc(big);
    char* R3 = (char*)alloc(big);
    char* R4 = (char*)alloc(big);
    float* gv_d = (float*)alloc((size_t)cBS * 64 * sizeof(float));  // 2 MB
    float* go_d = (float*)alloc((size_t)cBS * 64 * sizeof(float));  // 2 MB
    u16* selh = (u16*)alloc((size_t)128 * cD * sizeof(u16));        // 256 KB
    u16* sell = (u16*)alloc((size_t)128 * cD * sizeof(u16));        // 256 KB
    int* flags = (int*)alloc((size_t)cBS * 16 * sizeof(int));       // 512 KB
    int* counter = (int*)alloc(256);

    u16* WvT = (u16*)R1;
    float* lgp = (float*)(R1 + half);       // 12 MB partials (3 x 4 MB)
    float* q_t = (float*)R1;
    u16* xlo = (u16*)R2;
    float* k_t = (float*)R2;
    u16* WoT = (u16*)R2;
    u16* v_b = (u16*)R3;
    u16* Wqb = (u16*)(R3 + half);
    u16* Wkb = (u16*)(R3 + half + ((size_t)cD * cD * 2));
    u16* ctxh = (u16*)(R3 + half);
    u16* xh = (u16*)R4;
    u16* q_b = (u16*)R4;
    u16* k_b = (u16*)(R4 + half);

    hipMemsetAsync(counter, 0, sizeof(int), stream);

    // Phase 1: split casts, MFMA logits (bf16x3) + top2 + f32 tie repair
    k_cast_split<<<8192, 256, 0, stream>>>(x, xh, xlo);
    k_cast_split<<<64, 256, 0, stream>>>(sel_v, selh, sell);
    k_cast_split<<<64, 256, 0, stream>>>(sel_o, selh + (size_t)cHE * cD,
                                         sell + (size_t)cHE * cD);
    k_gemm_logits3<<<dim3(64, 3), 256, 0, stream>>>(xh, xlo, selh, sell, lgp);
    k_top2_flag<<<512, 256, 0, stream>>>(lgp, gv_d, go_d, flags, counter);
    k_repair<<<256, 64, 0, stream>>>(x, sel_v, sel_o, counter, flags, gv_d, go_d);

    // V-expert GEMM
    k_cast_wv<<<dim3(16, 64), 256, 0, stream>>>(Wv, WvT);
    k_gemm_v<<<dim3(64, 8), 256, 0, stream>>>(xh, WvT, gv_d, v_b);

    // Phase 2: Q/K projection (MFMA) + RoPE-cast + MFMA attention
    k_cast_f2b<<<1024, 256, 0, stream>>>(Wq, Wqb);
    k_cast_f2b<<<1024, 256, 0, stream>>>(Wk, Wkb);
    k_qkproj_mfma<<<dim3(64, 16), 256, 0, stream>>>(xh, Wqb, Wkb, q_t, k_t);
    k_rope_cast<<<(2 * cB * cH * cS * (cDH / 2)) / 256, 256, 0, stream>>>(
        q_t, k_t, positions, q_b, k_b);
    k_attn_mfma<<<dim3(16, 8, 4), 256, 0, stream>>>(q_b, k_b, v_b, ctxh);

    // Phase 3: O-expert GEMM
    k_cast_wo<<<dim3(16, 64), 256, 0, stream>>>(Wo, WoT);
    k_gemm_o<<<dim3(64, 8), 256, 0, stream>>>(ctxh, WoT, go_d, out);
}